// Round 8
// baseline (154.615 us; speedup 1.0000x reference)
//
#include <hip/hip_runtime.h>
#include <cstdint>
#include <cstddef>

#define DM 1024
#define NHEAD 16
#define DKH 64
#define SEQLEN 2048
#define NBATCH 2
#define MTOT (NBATCH * SEQLEN)  // 4096

typedef __attribute__((ext_vector_type(8))) short bf16x8;
typedef __attribute__((ext_vector_type(4))) float f32x4;
typedef __attribute__((ext_vector_type(16))) float f32x16;
typedef __attribute__((ext_vector_type(2))) unsigned int u32x2;

// (1/sqrt(Dk)) * log2(e): folded into Q projection; attn softmax uses exp2.
#define QSCALE 0.18033688011112042f

__device__ __forceinline__ uint16_t f2bf(float f) {
  uint32_t x = __float_as_uint(f);
  uint32_t r = x + 0x7FFFu + ((x >> 16) & 1u);  // RNE; inputs finite
  return (uint16_t)(r >> 16);
}

__device__ __forceinline__ uint32_t cvtpk(float a, float b) {
  uint32_t r;
  asm("v_cvt_pk_bf16_f32 %0, %1, %2" : "=v"(r) : "v"(a), "v"(b));
  return r;
}

__device__ __forceinline__ float exp2_fast(float x) {
  float r;
  asm("v_exp_f32 %0, %1" : "=v"(r) : "v"(x));
  return r;
}

__device__ __forceinline__ float max3f(float a, float b, float c) {
  float r;
  asm("v_max3_f32 %0, %1, %2, %3" : "=v"(r) : "v"(a), "v"(b), "v"(c));
  return r;
}

__device__ __forceinline__ void gload_lds16(const void* g, void* l) {
  __builtin_amdgcn_global_load_lds(
      (const __attribute__((address_space(1))) void*)g,
      (__attribute__((address_space(3))) void*)l, 16, 0, 0);
}

// Swizzle: 16B-slot XOR (bits 4-6) so 32-row column reads spread over 8 slots.
__device__ __forceinline__ int fsw(int r) { return ((r + (r >> 3)) & 7) << 4; }

// ---- fp32 -> bf16 convert, weights only (x-inputs converted inside gemm_qkv) ----
struct CvtArgs {
  const float* src[4];
  uint16_t* dst[4];
  int end4[4];  // cumulative float4 counts
};

__global__ void cvt_all_kernel(CvtArgs a) {
  int i = blockIdx.x * blockDim.x + threadIdx.x;
  int r = 0;
#pragma unroll
  for (int j = 0; j < 4; ++j)
    if (i >= a.end4[j]) r = j + 1;
  if (r >= 4) return;
  int local = i - (r == 0 ? 0 : a.end4[r - 1]);
  float4 v = reinterpret_cast<const float4*>(a.src[r])[local];
  uint64_t p = (uint64_t)f2bf(v.x) | ((uint64_t)f2bf(v.y) << 16) |
               ((uint64_t)f2bf(v.z) << 32) | ((uint64_t)f2bf(v.w) << 48);
  reinterpret_cast<uint64_t*>(a.dst[r])[local] = p;
}

// ---- fused QKV projection GEMM (2-phase dbuf; A read fp32 + cvt in staging) ----
// grid (M/128, 24): blockIdx.y>>3 selects projection (0=Q,1=K,2=V).
// C = A @ W^T + b; Q scaled by QSCALE; V written transposed to [b,h,d,s].
// Per K-step: after barrier issue B gload_lds(t+1) + A fp32 loads(t+1 -> regs);
// compute tile t; then cvt+ds_write A(t+1). HBM latency hides under compute.
__global__ __launch_bounds__(256)
void gemm_qkv(const float* __restrict__ xq, const float* __restrict__ xk,
              const float* __restrict__ xv, const uint16_t* __restrict__ wqkv,
              const float* __restrict__ bqp, const float* __restrict__ bkp,
              const float* __restrict__ bvp, uint16_t* __restrict__ Qp,
              uint16_t* __restrict__ Kp, uint16_t* __restrict__ VTp) {
  __shared__ uint16_t smem[2 * 2 * 128 * 64];  // 64 KiB: 2 bufs x (A 16K | B 16K)
  const int tid = threadIdx.x;
  const int wave = tid >> 6, lane = tid & 63;
  const int l15 = lane & 15, l4 = lane >> 4;
  const int proj = blockIdx.y >> 3;
  const int brow = blockIdx.x * 128, bcol = (blockIdx.y & 7) * 128;
  const int wr = (wave >> 1) * 64, wc = (wave & 1) * 64;
  const float* A = proj == 0 ? xq : proj == 1 ? xk : xv;
  const uint16_t* Bt = wqkv + (size_t)proj * DM * DM;
  const float* bias = proj == 0 ? bqp : proj == 1 ? bkp : bvp;

  // Per-thread A slice: row = tid>>1, 32 f32 at col (tid&1)*32 (within BK=64).
  const float* arow = A + (size_t)(brow + (tid >> 1)) * DM + (tid & 1) * 32;
  const int aldsoff = (tid >> 1) * 128 + (tid & 1) * 64;  // bytes within A region

  const f32x4 fzero = {0.f, 0.f, 0.f, 0.f};
  f32x4 acc[4][4];
#pragma unroll
  for (int m = 0; m < 4; ++m)
#pragma unroll
    for (int n = 0; n < 4; ++n) acc[m][n] = fzero;

  // Prologue: stage tile 0 into buf 0 (B via gload_lds, A via reg+cvt).
#pragma unroll
  for (int t = 0; t < 4; ++t) {
    const int o = t * 4096 + wave * 1024 + lane * 16;
    const int row = o >> 7, kk = (o & 127) >> 1;
    gload_lds16(Bt + (size_t)(bcol + row) * DM + kk,
                (char*)smem + 16384 + t * 4096 + wave * 1024);
  }
  {
    float4 av[8];
#pragma unroll
    for (int j = 0; j < 8; ++j) av[j] = *(const float4*)(arow + j * 4);
    char* ab = (char*)smem + aldsoff;
#pragma unroll
    for (int g = 0; g < 4; ++g) {
      uint4 w;
      w.x = cvtpk(av[2 * g].x, av[2 * g].y);
      w.y = cvtpk(av[2 * g].z, av[2 * g].w);
      w.z = cvtpk(av[2 * g + 1].x, av[2 * g + 1].y);
      w.w = cvtpk(av[2 * g + 1].z, av[2 * g + 1].w);
      *(uint4*)(ab + g * 16) = w;
    }
  }

  int cur = 0;
  for (int k0 = 0; k0 < DM; k0 += 64) {
    __syncthreads();  // buf[cur] staged; prior readers of buf[cur^1] done
    const bool hasNext = (k0 + 64 < DM);
    float4 av[8];
    if (hasNext) {
#pragma unroll
      for (int t = 0; t < 4; ++t) {
        const int o = t * 4096 + wave * 1024 + lane * 16;
        const int row = o >> 7, kk = (o & 127) >> 1;
        gload_lds16(Bt + (size_t)(bcol + row) * DM + (k0 + 64 + kk),
                    (char*)smem + (cur ^ 1) * 32768 + 16384 + t * 4096 + wave * 1024);
      }
#pragma unroll
      for (int j = 0; j < 8; ++j) av[j] = *(const float4*)(arow + k0 + 64 + j * 4);
    }

    const uint16_t* At = smem + cur * 16384;
    const uint16_t* Bs = At + 8192;
#pragma unroll
    for (int ks = 0; ks < 2; ++ks) {
      bf16x8 a[4], b[4];
#pragma unroll
      for (int m = 0; m < 4; ++m)
        a[m] = *(const bf16x8*)(At + (wr + m * 16 + l15) * 64 + ks * 32 + l4 * 8);
#pragma unroll
      for (int n = 0; n < 4; ++n)
        b[n] = *(const bf16x8*)(Bs + (wc + n * 16 + l15) * 64 + ks * 32 + l4 * 8);
#pragma unroll
      for (int m = 0; m < 4; ++m)
#pragma unroll
        for (int n = 0; n < 4; ++n)
          acc[m][n] = __builtin_amdgcn_mfma_f32_16x16x32_bf16(a[m], b[n], acc[m][n], 0, 0, 0);
    }

    if (hasNext) {
      char* ab = (char*)smem + (cur ^ 1) * 32768 + aldsoff;
#pragma unroll
      for (int g = 0; g < 4; ++g) {
        uint4 w;
        w.x = cvtpk(av[2 * g].x, av[2 * g].y);
        w.y = cvtpk(av[2 * g].z, av[2 * g].w);
        w.z = cvtpk(av[2 * g + 1].x, av[2 * g + 1].y);
        w.w = cvtpk(av[2 * g + 1].z, av[2 * g + 1].w);
        *(uint4*)(ab + g * 16) = w;
      }
    }
    cur ^= 1;
  }

  const float scale = proj == 0 ? QSCALE : 1.0f;
  uint16_t* dstQK = proj == 0 ? Qp : Kp;
#pragma unroll
  for (int m = 0; m < 4; ++m) {
#pragma unroll
    for (int n = 0; n < 4; ++n) {
      const int gcol = bcol + wc + n * 16 + l15;
      const float bv = bias[gcol];
      if (proj == 2) {
        // V^T: element (s=grow, col=gcol) -> VT[(b*NHEAD+h)*DKH + d][s].
        const int grow0 = brow + wr + m * 16 + l4 * 4;
        const int b_ = grow0 >> 11, s_ = grow0 & 2047;
        const int h_ = gcol >> 6, d_ = gcol & 63;
        uint16_t* dst = VTp + ((size_t)((b_ * NHEAD + h_) * DKH + d_)) * SEQLEN + s_;
        uint64_t pk = (uint64_t)f2bf(acc[m][n][0] + bv) |
                      ((uint64_t)f2bf(acc[m][n][1] + bv) << 16) |
                      ((uint64_t)f2bf(acc[m][n][2] + bv) << 32) |
                      ((uint64_t)f2bf(acc[m][n][3] + bv) << 48);
        *(uint64_t*)dst = pk;
      } else {
#pragma unroll
        for (int r = 0; r < 4; ++r) {
          const int grow = brow + wr + m * 16 + l4 * 4 + r;
          dstQK[(size_t)grow * DM + gcol] = f2bf((acc[m][n][r] + bv) * scale);
        }
      }
    }
  }
}

// Stage one 128x64 A-tile + 128x64 B-tile (32 KiB) into LDS buffer `buf`.
__device__ __forceinline__ void gemm_stage(const uint16_t* __restrict__ A,
                                           const uint16_t* __restrict__ Bt,
                                           int brow, int bcol, int k0,
                                           char* smem, int buf, int wave, int lane) {
#pragma unroll
  for (int t = 0; t < 8; ++t) {
    const int o = t * 4096 + wave * 1024 + lane * 16;
    const uint16_t* g;
    if (t < 4) {
      const int row = o >> 7, kk = (o & 127) >> 1;
      g = A + (size_t)(brow + row) * DM + (k0 + kk);
    } else {
      const int o2 = o - 16384;
      const int row = o2 >> 7, kk = (o2 & 127) >> 1;
      g = Bt + (size_t)(bcol + row) * DM + (k0 + kk);
    }
    gload_lds16(g, smem + buf * 32768 + t * 4096 + wave * 1024);
  }
}

// ---- output projection GEMM (f32 out, 2-phase double-buffered) ----
__global__ __launch_bounds__(256)
void gemm_out(const uint16_t* __restrict__ A, const uint16_t* __restrict__ Bt,
              const float* __restrict__ bias, float* __restrict__ C) {
  __shared__ uint16_t smem[2 * 2 * 128 * 64];  // 64 KiB
  const int tid = threadIdx.x;
  const int wave = tid >> 6, lane = tid & 63;
  const int l15 = lane & 15, l4 = lane >> 4;
  const int brow = blockIdx.x * 128, bcol = blockIdx.y * 128;
  const int wr = (wave >> 1) * 64, wc = (wave & 1) * 64;

  const f32x4 fzero = {0.f, 0.f, 0.f, 0.f};
  f32x4 acc[4][4];
#pragma unroll
  for (int m = 0; m < 4; ++m)
#pragma unroll
    for (int n = 0; n < 4; ++n) acc[m][n] = fzero;

  gemm_stage(A, Bt, brow, bcol, 0, (char*)smem, 0, wave, lane);
  int cur = 0;
  for (int k0 = 0; k0 < DM; k0 += 64) {
    __syncthreads();
    if (k0 + 64 < DM)
      gemm_stage(A, Bt, brow, bcol, k0 + 64, (char*)smem, cur ^ 1, wave, lane);
    const uint16_t* At = smem + cur * 16384;
    const uint16_t* Bs = At + 8192;
#pragma unroll
    for (int ks = 0; ks < 2; ++ks) {
      bf16x8 a[4], b[4];
#pragma unroll
      for (int m = 0; m < 4; ++m)
        a[m] = *(const bf16x8*)(At + (wr + m * 16 + l15) * 64 + ks * 32 + l4 * 8);
#pragma unroll
      for (int n = 0; n < 4; ++n)
        b[n] = *(const bf16x8*)(Bs + (wc + n * 16 + l15) * 64 + ks * 32 + l4 * 8);
#pragma unroll
      for (int m = 0; m < 4; ++m)
#pragma unroll
        for (int n = 0; n < 4; ++n)
          acc[m][n] = __builtin_amdgcn_mfma_f32_16x16x32_bf16(a[m], b[n], acc[m][n], 0, 0, 0);
    }
    cur ^= 1;
  }

#pragma unroll
  for (int m = 0; m < 4; ++m) {
#pragma unroll
    for (int n = 0; n < 4; ++n) {
      const int gcol = bcol + wc + n * 16 + l15;
      const float bv = bias[gcol];
#pragma unroll
      for (int r = 0; r < 4; ++r) {
        const int grow = brow + wr + m * 16 + l4 * 4 + r;
        C[(size_t)grow * DM + gcol] = acc[m][n][r] + bv;
      }
    }
  }
}

// ---- flash attention (round-6 structure): 32x32 MFMA, in-register P,
// KVBLK=64, 32 KiB LDS, MFMA row-sums, zero16 C-operand for QK chains ----
__device__ __forceinline__ void stage_kv(const uint16_t* __restrict__ Kg,
                                         const uint16_t* __restrict__ Vg,
                                         char* buf, int wave, int lane) {
#pragma unroll
  for (int i = 0; i < 2; ++i) {
    const int base = i * 4096 + wave * 1024;
    const int row = i * 32 + wave * 8 + (lane >> 3);
    const int esw = (((lane & 7) << 4) ^ fsw(row)) >> 1;
    gload_lds16(Kg + (size_t)row * DM + esw, buf + base);
    gload_lds16(Vg + (size_t)row * SEQLEN + esw, buf + 8192 + base);
  }
}

__global__ __launch_bounds__(256)
void attn_fwd_kernel(const uint16_t* __restrict__ Qp, const uint16_t* __restrict__ Kp,
                     const uint16_t* __restrict__ VTp, uint16_t* __restrict__ Op) {
  __shared__ __align__(16) char lds[32768];  // 2 bufs x (K 8KB | V^T 8KB)
  const int tid = threadIdx.x;
  const int wave = tid >> 6, lane = tid & 63;
  const int l31 = lane & 31, hi = lane >> 5;
  const int bb = blockIdx.z, h = blockIdx.y;
  const int q0 = blockIdx.x * 128;

  // Q (pre-scaled) in registers: qf[ds] = Q[qrow][ds*16 + hi*8 .. +8].
  const int qrow = q0 + wave * 32 + l31;
  const uint16_t* qb = Qp + ((size_t)(bb * SEQLEN + qrow)) * DM + h * DKH;
  bf16x8 qf[4];
#pragma unroll
  for (int ds = 0; ds < 4; ++ds)
    qf[ds] = *(const bf16x8*)(qb + ds * 16 + hi * 8);

  bf16x8 onesf;
#pragma unroll
  for (int j = 0; j < 8; ++j) onesf[j] = (short)0x3F80;  // bf16 1.0

  f32x16 oacc[2], lacc, zero16;
#pragma unroll
  for (int r = 0; r < 16; ++r) {
    oacc[0][r] = 0.f; oacc[1][r] = 0.f; lacc[r] = 0.f; zero16[r] = 0.f;
  }
  float mrow = -1e30f;

  const uint16_t* Kg = Kp + ((size_t)(bb * SEQLEN)) * DM + h * DKH;
  const uint16_t* Vg = VTp + ((size_t)((bb * NHEAD + h) * DKH)) * SEQLEN;

  stage_kv(Kg, Vg, lds, wave, lane);  // tile 0 -> buf 0

  const int NT = SEQLEN / 64;
  for (int t = 0; t < NT; ++t) {
    __syncthreads();  // tile t resident (vmcnt drained); buf t+1 free
    if (t + 1 < NT)
      stage_kv(Kg + (size_t)(t + 1) * 64 * DM, Vg + (t + 1) * 64,
               lds + ((t + 1) & 1) * 16384, wave, lane);
    const char* kb = lds + (t & 1) * 16384;
    const char* vb = kb + 8192;

    // S^T = K Q^T via 32x32x16 (8 MFMA), C-in from never-written zero16.
    f32x16 sacc[2];
    __builtin_amdgcn_s_setprio(1);
#pragma unroll
    for (int n = 0; n < 2; ++n) {
      const int kr = 32 * n + l31;
      const char* krow = kb + kr * 128;
      const int f = fsw(kr);
      const bf16x8 kf0 = *(const bf16x8*)(krow + ((hi * 16) ^ f));
      sacc[n] = __builtin_amdgcn_mfma_f32_32x32x16_bf16(kf0, qf[0], zero16, 0, 0, 0);
#pragma unroll
      for (int ds = 1; ds < 4; ++ds) {
        const bf16x8 kf = *(const bf16x8*)(krow + ((ds * 32 + hi * 16) ^ f));
        sacc[n] = __builtin_amdgcn_mfma_f32_32x32x16_bf16(kf, qf[ds], sacc[n], 0, 0, 0);
      }
    }
    __builtin_amdgcn_s_setprio(0);

    // Max-reduce via v_max3 trees, one cross-half shfl.
    float ma = max3f(sacc[0][0], sacc[0][1], sacc[0][2]);
    ma = max3f(ma, sacc[0][3], sacc[0][4]);
    ma = max3f(ma, sacc[0][5], sacc[0][6]);
    ma = max3f(ma, sacc[0][7], sacc[0][8]);
    ma = max3f(ma, sacc[0][9], sacc[0][10]);
    ma = max3f(ma, sacc[0][11], sacc[0][12]);
    ma = max3f(ma, sacc[0][13], sacc[0][14]);
    float mb = max3f(sacc[1][0], sacc[1][1], sacc[1][2]);
    mb = max3f(mb, sacc[1][3], sacc[1][4]);
    mb = max3f(mb, sacc[1][5], sacc[1][6]);
    mb = max3f(mb, sacc[1][7], sacc[1][8]);
    mb = max3f(mb, sacc[1][9], sacc[1][10]);
    mb = max3f(mb, sacc[1][11], sacc[1][12]);
    mb = max3f(mb, sacc[1][13], sacc[1][14]);
    float mx = max3f(fmaxf(ma, sacc[0][15]), mb, sacc[1][15]);
    mx = fmaxf(mx, __shfl_xor(mx, 32, 64));

    float mnew = mrow;
    if (__any(mx > mrow + 8.f)) {  // defer-max THR=8 (P bounded by 2^8)
      mnew = fmaxf(mrow, mx);
      const float scl = exp2_fast(mrow - mnew);
#pragma unroll
      for (int m = 0; m < 2; ++m)
#pragma unroll
        for (int r = 0; r < 16; ++r) oacc[m][r] *= scl;
      lacc[0] *= scl;
    }
    mrow = mnew;

#pragma unroll
    for (int n = 0; n < 2; ++n) {
      float pv[16];
#pragma unroll
      for (int r = 0; r < 16; ++r) pv[r] = exp2_fast(sacc[n][r] - mnew);
      // In-register P->bf16 fragments (T12): cvt_pk pairs + permlane32_swap
      // assemble contiguous k 0..15 (f0) / 16..31 (f1) B-fragments.
      const uint32_t c0 = cvtpk(pv[0], pv[1]),   c1 = cvtpk(pv[2], pv[3]);
      const uint32_t c2 = cvtpk(pv[4], pv[5]),   c3 = cvtpk(pv[6], pv[7]);
      const uint32_t c4 = cvtpk(pv[8], pv[9]),   c5 = cvtpk(pv[10], pv[11]);
      const uint32_t c6 = cvtpk(pv[12], pv[13]), c7 = cvtpk(pv[14], pv[15]);
      const u32x2 r02 = __builtin_amdgcn_permlane32_swap(c0, c2, false, false);
      const u32x2 r13 = __builtin_amdgcn_permlane32_swap(c1, c3, false, false);
      const u32x2 r46 = __builtin_amdgcn_permlane32_swap(c4, c6, false, false);
      const u32x2 r57 = __builtin_amdgcn_permlane32_swap(c5, c7, false, false);
      union { uint32_t w[4]; bf16x8 v; } f0, f1;
      f0.w[0] = r02.x; f0.w[1] = r13.x; f0.w[2] = r02.y; f0.w[3] = r13.y;
      f1.w[0] = r46.x; f1.w[1] = r57.x; f1.w[2] = r46.y; f1.w[3] = r57.y;

      // O^T += V^T P^T; l += 1^T P^T (row-sum on the MFMA pipe).
      __builtin_amdgcn_s_setprio(1);
#pragma unroll
      for (int m = 0; m < 2; ++m) {
        const int vr = 32 * m + l31;
        const char* vrow = vb + vr * 128;
        const int f = fsw(vr);
        const bf16x8 v0 = *(const bf16x8*)(vrow + ((n * 64 + hi * 16) ^ f));
        const bf16x8 v1 = *(const bf16x8*)(vrow + ((n * 64 + 32 + hi * 16) ^ f));
        oacc[m] = __builtin_amdgcn_mfma_f32_32x32x16_bf16(v0, f0.v, oacc[m], 0, 0, 0);
        oacc[m] = __builtin_amdgcn_mfma_f32_32x32x16_bf16(v1, f1.v, oacc[m], 0, 0, 0);
      }
      lacc = __builtin_amdgcn_mfma_f32_32x32x16_bf16(onesf, f0.v, lacc, 0, 0, 0);
      lacc = __builtin_amdgcn_mfma_f32_32x32x16_bf16(onesf, f1.v, lacc, 0, 0, 0);
      __builtin_amdgcn_s_setprio(0);
    }
  }

  // Normalize + store. oacc[m][r] = O^T[d][q=l31], d = 32m+(r&3)+8(r>>2)+4hi.
  const float il = 1.0f / lacc[0];
  uint16_t* ob = Op + ((size_t)(bb * SEQLEN + qrow)) * DM + h * DKH;
#pragma unroll
  for (int m = 0; m < 2; ++m)
#pragma unroll
    for (int rq = 0; rq < 4; ++rq) {
      const uint32_t w0 = cvtpk(oacc[m][4 * rq + 0] * il, oacc[m][4 * rq + 1] * il);
      const uint32_t w1 = cvtpk(oacc[m][4 * rq + 2] * il, oacc[m][4 * rq + 3] * il);
      *(uint64_t*)(ob + 32 * m + 8 * rq + 4 * hi) =
          (uint64_t)w0 | ((uint64_t)w1 << 32);
    }
}

extern "C" void kernel_launch(void* const* d_in, const int* in_sizes, int n_in,
                              void* d_out, int out_size, void* d_ws, size_t ws_size,
                              hipStream_t stream) {
  (void)in_sizes; (void)n_in; (void)out_size; (void)ws_size;
  const float* query = (const float*)d_in[0];
  const float* key_i = (const float*)d_in[1];
  const float* value = (const float*)d_in[2];
  const float* Wq = (const float*)d_in[3];
  const float* bq = (const float*)d_in[4];
  const float* Wk = (const float*)d_in[5];
  const float* bk = (const float*)d_in[6];
  const float* Wv = (const float*)d_in[7];
  const float* bv = (const float*)d_in[8];
  const float* Wo = (const float*)d_in[9];
  const float* bo = (const float*)d_in[10];
  float* out = (float*)d_out;

  char* ws = (char*)d_ws;
  const size_t MB = 1ull << 20;
  uint16_t* wqkv = (uint16_t*)(ws + 24 * MB);  // 3 x 2 MB contiguous (q,k,v)
  uint16_t* wob = (uint16_t*)(ws + 30 * MB);
  uint16_t* Qp  = (uint16_t*)(ws + 32 * MB);   // [s][dm], Q pre-scaled
  uint16_t* Kp  = (uint16_t*)(ws + 40 * MB);   // [s][dm]
  uint16_t* VTp = (uint16_t*)(ws + 48 * MB);   // [b,h,d,s]
  uint16_t* AO  = (uint16_t*)(ws + 56 * MB);   // [s][dm], ends at 64 MB

  const int n4w = (DM * DM) / 4;
  CvtArgs ca;
  ca.src[0] = Wq; ca.dst[0] = wqkv;
  ca.src[1] = Wk; ca.dst[1] = wqkv + DM * DM;
  ca.src[2] = Wv; ca.dst[2] = wqkv + 2 * DM * DM;
  ca.src[3] = Wo; ca.dst[3] = wob;
  int acc = 0;
  for (int j = 0; j < 4; ++j) { acc += n4w; ca.end4[j] = acc; }
  const int blk = 256;
  cvt_all_kernel<<<(acc + blk - 1) / blk, blk, 0, stream>>>(ca);

  dim3 gq(MTOT / 128, 24);  // 32 x 24 = 768 blocks, 3 projections fused
  gemm_qkv<<<gq, 256, 0, stream>>>(query, key_i, value, wqkv, bq, bk, bv, Qp, Kp, VTp);

  dim3 ga(SEQLEN / 128, NHEAD, NBATCH);  // 16 x 16 x 2 = 512 blocks
  attn_fwd_kernel<<<ga, 256, 0, stream>>>(Qp, Kp, VTp, AO);

  dim3 gg(MTOT / 128, DM / 128);  // 32 x 8
  gemm_out<<<gg, 256, 0, stream>>>(AO, wob, bo, out);
}

// Round 9
// 136.590 us; speedup vs baseline: 1.1320x; 1.1320x over previous
//
#include <hip/hip_runtime.h>
#include <cstdint>
#include <cstddef>

#define DM 1024
#define NHEAD 16
#define DKH 64
#define SEQLEN 2048
#define NBATCH 2
#define MTOT (NBATCH * SEQLEN)  // 4096

typedef __attribute__((ext_vector_type(8))) short bf16x8;
typedef __attribute__((ext_vector_type(4))) float f32x4;
typedef __attribute__((ext_vector_type(16))) float f32x16;
typedef __attribute__((ext_vector_type(2))) unsigned int u32x2;

// (1/sqrt(Dk)) * log2(e): folded into Q projection; attn softmax uses exp2.
#define QSCALE 0.18033688011112042f

__device__ __forceinline__ uint16_t f2bf(float f) {
  uint32_t x = __float_as_uint(f);
  uint32_t r = x + 0x7FFFu + ((x >> 16) & 1u);  // RNE; inputs finite
  return (uint16_t)(r >> 16);
}

__device__ __forceinline__ uint32_t cvtpk(float a, float b) {
  uint32_t r;
  asm("v_cvt_pk_bf16_f32 %0, %1, %2" : "=v"(r) : "v"(a), "v"(b));
  return r;
}

__device__ __forceinline__ float exp2_fast(float x) {
  float r;
  asm("v_exp_f32 %0, %1" : "=v"(r) : "v"(x));
  return r;
}

__device__ __forceinline__ float max3f(float a, float b, float c) {
  float r;
  asm("v_max3_f32 %0, %1, %2, %3" : "=v"(r) : "v"(a), "v"(b), "v"(c));
  return r;
}

__device__ __forceinline__ void gload_lds16(const void* g, void* l) {
  __builtin_amdgcn_global_load_lds(
      (const __attribute__((address_space(1))) void*)g,
      (__attribute__((address_space(3))) void*)l, 16, 0, 0);
}

// Swizzle: 16B-slot XOR (bits 4-6) so 32-row column reads spread over 8 slots.
__device__ __forceinline__ int fsw(int r) { return ((r + (r >> 3)) & 7) << 4; }

// ---- fused fp32 -> bf16 convert over 7 regions in one launch ----
struct CvtArgs {
  const float* src[7];
  uint16_t* dst[7];
  int end4[7];  // cumulative float4 counts
};

__global__ void cvt_all_kernel(CvtArgs a) {
  int i = blockIdx.x * blockDim.x + threadIdx.x;
  int r = 0;
#pragma unroll
  for (int j = 0; j < 7; ++j)
    if (i >= a.end4[j]) r = j + 1;
  if (r >= 7) return;
  int local = i - (r == 0 ? 0 : a.end4[r - 1]);
  float4 v = reinterpret_cast<const float4*>(a.src[r])[local];
  uint64_t p = (uint64_t)f2bf(v.x) | ((uint64_t)f2bf(v.y) << 16) |
               ((uint64_t)f2bf(v.z) << 32) | ((uint64_t)f2bf(v.w) << 48);
  reinterpret_cast<uint64_t*>(a.dst[r])[local] = p;
}

// Stage one 128x64 A-tile + 128x64 B-tile (32 KiB) into LDS buffer `buf`.
// T3-min 2-phase: called for tile t+1 BEFORE computing tile t.
__device__ __forceinline__ void gemm_stage(const uint16_t* __restrict__ A,
                                           const uint16_t* __restrict__ Bt,
                                           int brow, int bcol, int k0,
                                           char* smem, int buf, int wave, int lane) {
#pragma unroll
  for (int t = 0; t < 8; ++t) {
    const int o = t * 4096 + wave * 1024 + lane * 16;
    const uint16_t* g;
    if (t < 4) {
      const int row = o >> 7, kk = (o & 127) >> 1;
      g = A + (size_t)(brow + row) * DM + (k0 + kk);
    } else {
      const int o2 = o - 16384;
      const int row = o2 >> 7, kk = (o2 & 127) >> 1;
      g = Bt + (size_t)(bcol + row) * DM + (k0 + kk);
    }
    gload_lds16(g, smem + buf * 32768 + t * 4096 + wave * 1024);
  }
}

// ---- fused QKV projection GEMM (2-phase double-buffered, bf16 inputs) ----
// 1D grid of 768 blocks, XCD-chunked swizzle (96 consecutive work-units/XCD
// so blocks sharing a weight panel land on one XCD's L2).
// C = A @ W^T + b; Q scaled by QSCALE; V written transposed to [b,h,d,s].
__global__ __launch_bounds__(256)
void gemm_qkv(const uint16_t* __restrict__ xq, const uint16_t* __restrict__ xk,
              const uint16_t* __restrict__ xv, const uint16_t* __restrict__ wqkv,
              const float* __restrict__ bqp, const float* __restrict__ bkp,
              const float* __restrict__ bvp, uint16_t* __restrict__ Qp,
              uint16_t* __restrict__ Kp, uint16_t* __restrict__ VTp) {
  __shared__ uint16_t smem[2 * 2 * 128 * 64];  // 64 KiB: 2 bufs x (A|B)
  const int swz = (blockIdx.x & 7) * 96 + (blockIdx.x >> 3);  // bijective, 768%8==0
  const int bx = swz & 31, by = swz >> 5;
  const int tid = threadIdx.x;
  const int wave = tid >> 6, lane = tid & 63;
  const int l15 = lane & 15, l4 = lane >> 4;
  const int proj = by >> 3;
  const int brow = bx * 128, bcol = (by & 7) * 128;
  const int wr = (wave >> 1) * 64, wc = (wave & 1) * 64;
  const uint16_t* A = proj == 0 ? xq : proj == 1 ? xk : xv;
  const uint16_t* Bt = wqkv + (size_t)proj * DM * DM;
  const float* bias = proj == 0 ? bqp : proj == 1 ? bkp : bvp;

  const f32x4 fzero = {0.f, 0.f, 0.f, 0.f};
  f32x4 acc[4][4];
#pragma unroll
  for (int m = 0; m < 4; ++m)
#pragma unroll
    for (int n = 0; n < 4; ++n) acc[m][n] = fzero;

  gemm_stage(A, Bt, brow, bcol, 0, (char*)smem, 0, wave, lane);
  int cur = 0;
  for (int k0 = 0; k0 < DM; k0 += 64) {
    __syncthreads();  // loads for buf[cur] drained; buf[cur^1] free of readers
    if (k0 + 64 < DM)
      gemm_stage(A, Bt, brow, bcol, k0 + 64, (char*)smem, cur ^ 1, wave, lane);
    const uint16_t* At = smem + cur * 16384;
    const uint16_t* Bs = At + 8192;
#pragma unroll
    for (int ks = 0; ks < 2; ++ks) {
      bf16x8 a[4], b[4];
#pragma unroll
      for (int m = 0; m < 4; ++m)
        a[m] = *(const bf16x8*)(At + (wr + m * 16 + l15) * 64 + ks * 32 + l4 * 8);
#pragma unroll
      for (int n = 0; n < 4; ++n)
        b[n] = *(const bf16x8*)(Bs + (wc + n * 16 + l15) * 64 + ks * 32 + l4 * 8);
#pragma unroll
      for (int m = 0; m < 4; ++m)
#pragma unroll
        for (int n = 0; n < 4; ++n)
          acc[m][n] = __builtin_amdgcn_mfma_f32_16x16x32_bf16(a[m], b[n], acc[m][n], 0, 0, 0);
    }
    cur ^= 1;
  }

  const float scale = proj == 0 ? QSCALE : 1.0f;
  uint16_t* dstQK = proj == 0 ? Qp : Kp;
#pragma unroll
  for (int m = 0; m < 4; ++m) {
#pragma unroll
    for (int n = 0; n < 4; ++n) {
      const int gcol = bcol + wc + n * 16 + l15;
      const float bv = bias[gcol];
      if (proj == 2) {
        // V^T: element (s=grow, col=gcol) -> VT[(b*NHEAD+h)*DKH + d][s].
        const int grow0 = brow + wr + m * 16 + l4 * 4;
        const int b_ = grow0 >> 11, s_ = grow0 & 2047;
        const int h_ = gcol >> 6, d_ = gcol & 63;
        uint16_t* dst = VTp + ((size_t)((b_ * NHEAD + h_) * DKH + d_)) * SEQLEN + s_;
        uint64_t pk = (uint64_t)f2bf(acc[m][n][0] + bv) |
                      ((uint64_t)f2bf(acc[m][n][1] + bv) << 16) |
                      ((uint64_t)f2bf(acc[m][n][2] + bv) << 32) |
                      ((uint64_t)f2bf(acc[m][n][3] + bv) << 48);
        *(uint64_t*)dst = pk;
      } else {
#pragma unroll
        for (int r = 0; r < 4; ++r) {
          const int grow = brow + wr + m * 16 + l4 * 4 + r;
          dstQK[(size_t)grow * DM + gcol] = f2bf((acc[m][n][r] + bv) * scale);
        }
      }
    }
  }
}

// ---- output projection GEMM (f32 out, 2-phase double-buffered) ----
// 1D grid 256 blocks; XCD-chunked swizzle: each XCD owns one 128-col panel.
__global__ __launch_bounds__(256)
void gemm_out(const uint16_t* __restrict__ A, const uint16_t* __restrict__ Bt,
              const float* __restrict__ bias, float* __restrict__ C) {
  __shared__ uint16_t smem[2 * 2 * 128 * 64];  // 64 KiB
  const int swz = (blockIdx.x & 7) * 32 + (blockIdx.x >> 3);  // 256%8==0
  const int tid = threadIdx.x;
  const int wave = tid >> 6, lane = tid & 63;
  const int l15 = lane & 15, l4 = lane >> 4;
  const int brow = (swz & 31) * 128, bcol = (swz >> 5) * 128;
  const int wr = (wave >> 1) * 64, wc = (wave & 1) * 64;

  const f32x4 fzero = {0.f, 0.f, 0.f, 0.f};
  f32x4 acc[4][4];
#pragma unroll
  for (int m = 0; m < 4; ++m)
#pragma unroll
    for (int n = 0; n < 4; ++n) acc[m][n] = fzero;

  gemm_stage(A, Bt, brow, bcol, 0, (char*)smem, 0, wave, lane);
  int cur = 0;
  for (int k0 = 0; k0 < DM; k0 += 64) {
    __syncthreads();
    if (k0 + 64 < DM)
      gemm_stage(A, Bt, brow, bcol, k0 + 64, (char*)smem, cur ^ 1, wave, lane);
    const uint16_t* At = smem + cur * 16384;
    const uint16_t* Bs = At + 8192;
#pragma unroll
    for (int ks = 0; ks < 2; ++ks) {
      bf16x8 a[4], b[4];
#pragma unroll
      for (int m = 0; m < 4; ++m)
        a[m] = *(const bf16x8*)(At + (wr + m * 16 + l15) * 64 + ks * 32 + l4 * 8);
#pragma unroll
      for (int n = 0; n < 4; ++n)
        b[n] = *(const bf16x8*)(Bs + (wc + n * 16 + l15) * 64 + ks * 32 + l4 * 8);
#pragma unroll
      for (int m = 0; m < 4; ++m)
#pragma unroll
        for (int n = 0; n < 4; ++n)
          acc[m][n] = __builtin_amdgcn_mfma_f32_16x16x32_bf16(a[m], b[n], acc[m][n], 0, 0, 0);
    }
    cur ^= 1;
  }

#pragma unroll
  for (int m = 0; m < 4; ++m) {
#pragma unroll
    for (int n = 0; n < 4; ++n) {
      const int gcol = bcol + wc + n * 16 + l15;
      const float bv = bias[gcol];
#pragma unroll
      for (int r = 0; r < 4; ++r) {
        const int grow = brow + wr + m * 16 + l4 * 4 + r;
        C[(size_t)grow * DM + gcol] = acc[m][n][r] + bv;
      }
    }
  }
}

// ---- flash attention: 32x32 MFMA, in-register P, KVBLK=64, 32 KiB LDS,
// MFMA row-sums, zero16 C-operand for QK chains, XCD-chunked block swizzle
// (16 consecutive q-blocks of one (b,h) land on one XCD -> K/V L2 reuse) ----
__device__ __forceinline__ void stage_kv(const uint16_t* __restrict__ Kg,
                                         const uint16_t* __restrict__ Vg,
                                         char* buf, int wave, int lane) {
#pragma unroll
  for (int i = 0; i < 2; ++i) {
    const int base = i * 4096 + wave * 1024;
    const int row = i * 32 + wave * 8 + (lane >> 3);
    const int esw = (((lane & 7) << 4) ^ fsw(row)) >> 1;
    gload_lds16(Kg + (size_t)row * DM + esw, buf + base);
    gload_lds16(Vg + (size_t)row * SEQLEN + esw, buf + 8192 + base);
  }
}

__global__ __launch_bounds__(256)
void attn_fwd_kernel(const uint16_t* __restrict__ Qp, const uint16_t* __restrict__ Kp,
                     const uint16_t* __restrict__ VTp, uint16_t* __restrict__ Op) {
  __shared__ __align__(16) char lds[32768];  // 2 bufs x (K 8KB | V^T 8KB)
  const int swz = (blockIdx.x & 7) * 64 + (blockIdx.x >> 3);  // 512%8==0
  const int bb = swz >> 8, h = (swz >> 4) & 15;
  const int q0 = (swz & 15) * 128;
  const int tid = threadIdx.x;
  const int wave = tid >> 6, lane = tid & 63;
  const int l31 = lane & 31, hi = lane >> 5;

  // Q (pre-scaled) in registers: qf[ds] = Q[qrow][ds*16 + hi*8 .. +8].
  const int qrow = q0 + wave * 32 + l31;
  const uint16_t* qb = Qp + ((size_t)(bb * SEQLEN + qrow)) * DM + h * DKH;
  bf16x8 qf[4];
#pragma unroll
  for (int ds = 0; ds < 4; ++ds)
    qf[ds] = *(const bf16x8*)(qb + ds * 16 + hi * 8);

  bf16x8 onesf;
#pragma unroll
  for (int j = 0; j < 8; ++j) onesf[j] = (short)0x3F80;  // bf16 1.0

  f32x16 oacc[2], lacc, zero16;
#pragma unroll
  for (int r = 0; r < 16; ++r) {
    oacc[0][r] = 0.f; oacc[1][r] = 0.f; lacc[r] = 0.f; zero16[r] = 0.f;
  }
  float mrow = -1e30f;

  const uint16_t* Kg = Kp + ((size_t)(bb * SEQLEN)) * DM + h * DKH;
  const uint16_t* Vg = VTp + ((size_t)((bb * NHEAD + h) * DKH)) * SEQLEN;

  stage_kv(Kg, Vg, lds, wave, lane);  // tile 0 -> buf 0

  const int NT = SEQLEN / 64;
  for (int t = 0; t < NT; ++t) {
    __syncthreads();  // tile t resident (vmcnt drained); buf t+1 free
    if (t + 1 < NT)
      stage_kv(Kg + (size_t)(t + 1) * 64 * DM, Vg + (t + 1) * 64,
               lds + ((t + 1) & 1) * 16384, wave, lane);
    const char* kb = lds + (t & 1) * 16384;
    const char* vb = kb + 8192;

    // S^T = K Q^T via 32x32x16 (8 MFMA), C-in from never-written zero16.
    f32x16 sacc[2];
    __builtin_amdgcn_s_setprio(1);
#pragma unroll
    for (int n = 0; n < 2; ++n) {
      const int kr = 32 * n + l31;
      const char* krow = kb + kr * 128;
      const int f = fsw(kr);
      const bf16x8 kf0 = *(const bf16x8*)(krow + ((hi * 16) ^ f));
      sacc[n] = __builtin_amdgcn_mfma_f32_32x32x16_bf16(kf0, qf[0], zero16, 0, 0, 0);
#pragma unroll
      for (int ds = 1; ds < 4; ++ds) {
        const bf16x8 kf = *(const bf16x8*)(krow + ((ds * 32 + hi * 16) ^ f));
        sacc[n] = __builtin_amdgcn_mfma_f32_32x32x16_bf16(kf, qf[ds], sacc[n], 0, 0, 0);
      }
    }
    __builtin_amdgcn_s_setprio(0);

    // Max-reduce via v_max3 trees, one cross-half shfl.
    float ma = max3f(sacc[0][0], sacc[0][1], sacc[0][2]);
    ma = max3f(ma, sacc[0][3], sacc[0][4]);
    ma = max3f(ma, sacc[0][5], sacc[0][6]);
    ma = max3f(ma, sacc[0][7], sacc[0][8]);
    ma = max3f(ma, sacc[0][9], sacc[0][10]);
    ma = max3f(ma, sacc[0][11], sacc[0][12]);
    ma = max3f(ma, sacc[0][13], sacc[0][14]);
    float mb = max3f(sacc[1][0], sacc[1][1], sacc[1][2]);
    mb = max3f(mb, sacc[1][3], sacc[1][4]);
    mb = max3f(mb, sacc[1][5], sacc[1][6]);
    mb = max3f(mb, sacc[1][7], sacc[1][8]);
    mb = max3f(mb, sacc[1][9], sacc[1][10]);
    mb = max3f(mb, sacc[1][11], sacc[1][12]);
    mb = max3f(mb, sacc[1][13], sacc[1][14]);
    float mx = max3f(fmaxf(ma, sacc[0][15]), mb, sacc[1][15]);
    mx = fmaxf(mx, __shfl_xor(mx, 32, 64));

    float mnew = mrow;
    if (__any(mx > mrow + 8.f)) {  // defer-max THR=8 (P bounded by 2^8)
      mnew = fmaxf(mrow, mx);
      const float scl = exp2_fast(mrow - mnew);
#pragma unroll
      for (int m = 0; m < 2; ++m)
#pragma unroll
        for (int r = 0; r < 16; ++r) oacc[m][r] *= scl;
      lacc[0] *= scl;
    }
    mrow = mnew;

#pragma unroll
    for (int n = 0; n < 2; ++n) {
      float pv[16];
#pragma unroll
      for (int r = 0; r < 16; ++r) pv[r] = exp2_fast(sacc[n][r] - mnew);
      // In-register P->bf16 fragments (T12): cvt_pk pairs + permlane32_swap
      // assemble contiguous k 0..15 (f0) / 16..31 (f1) B-fragments.
      const uint32_t c0 = cvtpk(pv[0], pv[1]),   c1 = cvtpk(pv[2], pv[3]);
      const uint32_t c2 = cvtpk(pv[4], pv[5]),   c3 = cvtpk(pv[6], pv[7]);
      const uint32_t c4 = cvtpk(pv[8], pv[9]),   c5 = cvtpk(pv[10], pv[11]);
      const uint32_t c6 = cvtpk(pv[12], pv[13]), c7 = cvtpk(pv[14], pv[15]);
      const u32x2 r02 = __builtin_amdgcn_permlane32_swap(c0, c2, false, false);
      const u32x2 r13 = __builtin_amdgcn_permlane32_swap(c1, c3, false, false);
      const u32x2 r46 = __builtin_amdgcn_permlane32_swap(c4, c6, false, false);
      const u32x2 r57 = __builtin_amdgcn_permlane32_swap(c5, c7, false, false);
      union { uint32_t w[4]; bf16x8 v; } f0, f1;
      f0.w[0] = r02.x; f0.w[1] = r13.x; f0.w[2] = r02.y; f0.w[3] = r13.y;
      f1.w[0] = r46.x; f1.w[1] = r57.x; f1.w[2] = r46.y; f1.w[3] = r57.y;

      // O^T += V^T P^T; l += 1^T P^T (row-sum on the MFMA pipe).
      __builtin_amdgcn_s_setprio(1);
#pragma unroll
      for (int m = 0; m < 2; ++m) {
        const int vr = 32 * m + l31;
        const char* vrow = vb + vr * 128;
        const int f = fsw(vr);
        const bf16x8 v0 = *(const bf16x8*)(vrow + ((n * 64 + hi * 16) ^ f));
        const bf16x8 v1 = *(const bf16x8*)(vrow + ((n * 64 + 32 + hi * 16) ^ f));
        oacc[m] = __builtin_amdgcn_mfma_f32_32x32x16_bf16(v0, f0.v, oacc[m], 0, 0, 0);
        oacc[m] = __builtin_amdgcn_mfma_f32_32x32x16_bf16(v1, f1.v, oacc[m], 0, 0, 0);
      }
      lacc = __builtin_amdgcn_mfma_f32_32x32x16_bf16(onesf, f0.v, lacc, 0, 0, 0);
      lacc = __builtin_amdgcn_mfma_f32_32x32x16_bf16(onesf, f1.v, lacc, 0, 0, 0);
      __builtin_amdgcn_s_setprio(0);
    }
  }

  // Normalize + store. oacc[m][r] = O^T[d][q=l31], d = 32m+(r&3)+8(r>>2)+4hi.
  const float il = 1.0f / lacc[0];
  uint16_t* ob = Op + ((size_t)(bb * SEQLEN + qrow)) * DM + h * DKH;
#pragma unroll
  for (int m = 0; m < 2; ++m)
#pragma unroll
    for (int rq = 0; rq < 4; ++rq) {
      const uint32_t w0 = cvtpk(oacc[m][4 * rq + 0] * il, oacc[m][4 * rq + 1] * il);
      const uint32_t w1 = cvtpk(oacc[m][4 * rq + 2] * il, oacc[m][4 * rq + 3] * il);
      *(uint64_t*)(ob + 32 * m + 8 * rq + 4 * hi) =
          (uint64_t)w0 | ((uint64_t)w1 << 32);
    }
}

extern "C" void kernel_launch(void* const* d_in, const int* in_sizes, int n_in,
                              void* d_out, int out_size, void* d_ws, size_t ws_size,
                              hipStream_t stream) {
  (void)in_sizes; (void)n_in; (void)out_size; (void)ws_size;
  const float* query = (const float*)d_in[0];
  const float* key_i = (const float*)d_in[1];
  const float* value = (const float*)d_in[2];
  const float* Wq = (const float*)d_in[3];
  const float* bq = (const float*)d_in[4];
  const float* Wk = (const float*)d_in[5];
  const float* bk = (const float*)d_in[6];
  const float* Wv = (const float*)d_in[7];
  const float* bv = (const float*)d_in[8];
  const float* Wo = (const float*)d_in[9];
  const float* bo = (const float*)d_in[10];
  float* out = (float*)d_out;

  char* ws = (char*)d_ws;
  const size_t MB = 1ull << 20;
  uint16_t* xq  = (uint16_t*)(ws + 0 * MB);    // 8 MB each (4096x1024 bf16)
  uint16_t* xk  = (uint16_t*)(ws + 8 * MB);
  uint16_t* xv  = (uint16_t*)(ws + 16 * MB);
  uint16_t* wqkv = (uint16_t*)(ws + 24 * MB);  // 3 x 2 MB contiguous (q,k,v)
  uint16_t* wob = (uint16_t*)(ws + 30 * MB);
  uint16_t* Qp  = (uint16_t*)(ws + 32 * MB);   // [s][dm], Q pre-scaled
  uint16_t* Kp  = (uint16_t*)(ws + 40 * MB);   // [s][dm]
  uint16_t* VTp = (uint16_t*)(ws + 48 * MB);   // [b,h,d,s]
  uint16_t* AO  = (uint16_t*)(ws + 56 * MB);   // [s][dm], ends at 64 MB

  const int n4x = (MTOT * DM) / 4;
  const int n4w = (DM * DM) / 4;
  CvtArgs ca;
  ca.src[0] = query; ca.dst[0] = xq;
  ca.src[1] = key_i; ca.dst[1] = xk;
  ca.src[2] = value; ca.dst[2] = xv;
  ca.src[3] = Wq;    ca.dst[3] = wqkv;
  ca.src[4] = Wk;    ca.dst[4] = wqkv + DM * DM;
  ca.src[5] = Wv;    ca.dst[5] = wqkv + 2 * DM * DM;
  ca.src[6] = Wo;    ca.dst[6] = wob;
  int acc = 0;
  for (int j = 0; j < 7; ++j) { acc += (j < 3) ? n4x : n4w; ca.end4[j] = acc; }
  const int blk = 256;
  cvt_all_kernel<<<(acc + blk - 1) / blk, blk, 0, stream>>>(ca);

  gemm_qkv<<<768, 256, 0, stream>>>(xq, xk, xv, wqkv, bq, bk, bv, Qp, Kp, VTp);

  attn_fwd_kernel<<<512, 256, 0, stream>>>(Qp, Kp, VTp, AO);

  gemm_out<<<256, 256, 0, stream>>>(AO, wob, bo, out);
}

// Round 10
// 126.749 us; speedup vs baseline: 1.2199x; 1.0776x over previous
//
#include <hip/hip_runtime.h>
#include <cstdint>
#include <cstddef>

#define DM 1024
#define NHEAD 16
#define DKH 64
#define SEQLEN 2048
#define NBATCH 2
#define MTOT (NBATCH * SEQLEN)  // 4096

typedef __attribute__((ext_vector_type(8))) short bf16x8;
typedef __attribute__((ext_vector_type(4))) float f32x4;
typedef __attribute__((ext_vector_type(16))) float f32x16;
typedef __attribute__((ext_vector_type(2))) unsigned int u32x2;

// (1/sqrt(Dk)) * log2(e): folded into Q projection; attn softmax uses exp2.
#define QSCALE 0.18033688011112042f

__device__ __forceinline__ uint16_t f2bf(float f) {
  uint32_t x = __float_as_uint(f);
  uint32_t r = x + 0x7FFFu + ((x >> 16) & 1u);  // RNE; inputs finite
  return (uint16_t)(r >> 16);
}

__device__ __forceinline__ uint32_t cvtpk(float a, float b) {
  uint32_t r;
  asm("v_cvt_pk_bf16_f32 %0, %1, %2" : "=v"(r) : "v"(a), "v"(b));
  return r;
}

__device__ __forceinline__ float exp2_fast(float x) {
  float r;
  asm("v_exp_f32 %0, %1" : "=v"(r) : "v"(x));
  return r;
}

__device__ __forceinline__ float max3f(float a, float b, float c) {
  float r;
  asm("v_max3_f32 %0, %1, %2, %3" : "=v"(r) : "v"(a), "v"(b), "v"(c));
  return r;
}

__device__ __forceinline__ void gload_lds16(const void* g, void* l) {
  __builtin_amdgcn_global_load_lds(
      (const __attribute__((address_space(1))) void*)g,
      (__attribute__((address_space(3))) void*)l, 16, 0, 0);
}

// Swizzle: 16B-slot XOR (bits 4-6) so 32-row column reads spread over 8 slots.
__device__ __forceinline__ int fsw(int r) { return ((r + (r >> 3)) & 7) << 4; }

// ---- fused fp32 -> bf16 convert over 7 regions in one launch ----
struct CvtArgs {
  const float* src[7];
  uint16_t* dst[7];
  int end4[7];  // cumulative float4 counts
};

__global__ void cvt_all_kernel(CvtArgs a) {
  int i = blockIdx.x * blockDim.x + threadIdx.x;
  int r = 0;
#pragma unroll
  for (int j = 0; j < 7; ++j)
    if (i >= a.end4[j]) r = j + 1;
  if (r >= 7) return;
  int local = i - (r == 0 ? 0 : a.end4[r - 1]);
  float4 v = reinterpret_cast<const float4*>(a.src[r])[local];
  uint64_t p = (uint64_t)f2bf(v.x) | ((uint64_t)f2bf(v.y) << 16) |
               ((uint64_t)f2bf(v.z) << 32) | ((uint64_t)f2bf(v.w) << 48);
  reinterpret_cast<uint64_t*>(a.dst[r])[local] = p;
}

// Stage one 128x64 A-tile + 128x64 B-tile (32 KiB) into LDS buffer `buf`.
// T3-min 2-phase: called for tile t+1 BEFORE computing tile t.
__device__ __forceinline__ void gemm_stage(const uint16_t* __restrict__ A,
                                           const uint16_t* __restrict__ Bt,
                                           int brow, int bcol, int k0,
                                           char* smem, int buf, int wave, int lane) {
#pragma unroll
  for (int t = 0; t < 8; ++t) {
    const int o = t * 4096 + wave * 1024 + lane * 16;
    const uint16_t* g;
    if (t < 4) {
      const int row = o >> 7, kk = (o & 127) >> 1;
      g = A + (size_t)(brow + row) * DM + (k0 + kk);
    } else {
      const int o2 = o - 16384;
      const int row = o2 >> 7, kk = (o2 & 127) >> 1;
      g = Bt + (size_t)(bcol + row) * DM + (k0 + kk);
    }
    gload_lds16(g, smem + buf * 32768 + t * 4096 + wave * 1024);
  }
}

// ---- fused QKV projection GEMM (2-phase double-buffered, bf16 inputs) ----
// grid (M/128, 24): blockIdx.y>>3 selects projection (0=Q,1=K,2=V).
// C = A @ W^T + b; Q scaled by QSCALE; V written transposed to [b,h,d,s].
__global__ __launch_bounds__(256)
void gemm_qkv(const uint16_t* __restrict__ xq, const uint16_t* __restrict__ xk,
              const uint16_t* __restrict__ xv, const uint16_t* __restrict__ wqkv,
              const float* __restrict__ bqp, const float* __restrict__ bkp,
              const float* __restrict__ bvp, uint16_t* __restrict__ Qp,
              uint16_t* __restrict__ Kp, uint16_t* __restrict__ VTp) {
  __shared__ uint16_t smem[2 * 2 * 128 * 64];  // 64 KiB: 2 bufs x (A|B)
  const int tid = threadIdx.x;
  const int wave = tid >> 6, lane = tid & 63;
  const int l15 = lane & 15, l4 = lane >> 4;
  const int proj = blockIdx.y >> 3;
  const int brow = blockIdx.x * 128, bcol = (blockIdx.y & 7) * 128;
  const int wr = (wave >> 1) * 64, wc = (wave & 1) * 64;
  const uint16_t* A = proj == 0 ? xq : proj == 1 ? xk : xv;
  const uint16_t* Bt = wqkv + (size_t)proj * DM * DM;
  const float* bias = proj == 0 ? bqp : proj == 1 ? bkp : bvp;

  const f32x4 fzero = {0.f, 0.f, 0.f, 0.f};
  f32x4 acc[4][4];
#pragma unroll
  for (int m = 0; m < 4; ++m)
#pragma unroll
    for (int n = 0; n < 4; ++n) acc[m][n] = fzero;

  gemm_stage(A, Bt, brow, bcol, 0, (char*)smem, 0, wave, lane);
  int cur = 0;
  for (int k0 = 0; k0 < DM; k0 += 64) {
    __syncthreads();  // loads for buf[cur] drained; buf[cur^1] free of readers
    if (k0 + 64 < DM)
      gemm_stage(A, Bt, brow, bcol, k0 + 64, (char*)smem, cur ^ 1, wave, lane);
    const uint16_t* At = smem + cur * 16384;
    const uint16_t* Bs = At + 8192;
#pragma unroll
    for (int ks = 0; ks < 2; ++ks) {
      bf16x8 a[4], b[4];
#pragma unroll
      for (int m = 0; m < 4; ++m)
        a[m] = *(const bf16x8*)(At + (wr + m * 16 + l15) * 64 + ks * 32 + l4 * 8);
#pragma unroll
      for (int n = 0; n < 4; ++n)
        b[n] = *(const bf16x8*)(Bs + (wc + n * 16 + l15) * 64 + ks * 32 + l4 * 8);
#pragma unroll
      for (int m = 0; m < 4; ++m)
#pragma unroll
        for (int n = 0; n < 4; ++n)
          acc[m][n] = __builtin_amdgcn_mfma_f32_16x16x32_bf16(a[m], b[n], acc[m][n], 0, 0, 0);
    }
    cur ^= 1;
  }

  const float scale = proj == 0 ? QSCALE : 1.0f;
  uint16_t* dstQK = proj == 0 ? Qp : Kp;
#pragma unroll
  for (int m = 0; m < 4; ++m) {
#pragma unroll
    for (int n = 0; n < 4; ++n) {
      const int gcol = bcol + wc + n * 16 + l15;
      const float bv = bias[gcol];
      if (proj == 2) {
        // V^T: element (s=grow, col=gcol) -> VT[(b*NHEAD+h)*DKH + d][s].
        const int grow0 = brow + wr + m * 16 + l4 * 4;
        const int b_ = grow0 >> 11, s_ = grow0 & 2047;
        const int h_ = gcol >> 6, d_ = gcol & 63;
        uint16_t* dst = VTp + ((size_t)((b_ * NHEAD + h_) * DKH + d_)) * SEQLEN + s_;
        uint64_t pk = (uint64_t)f2bf(acc[m][n][0] + bv) |
                      ((uint64_t)f2bf(acc[m][n][1] + bv) << 16) |
                      ((uint64_t)f2bf(acc[m][n][2] + bv) << 32) |
                      ((uint64_t)f2bf(acc[m][n][3] + bv) << 48);
        *(uint64_t*)dst = pk;
      } else {
#pragma unroll
        for (int r = 0; r < 4; ++r) {
          const int grow = brow + wr + m * 16 + l4 * 4 + r;
          dstQK[(size_t)grow * DM + gcol] = f2bf((acc[m][n][r] + bv) * scale);
        }
      }
    }
  }
}

// ---- output projection GEMM (f32 out, 2-phase double-buffered) ----
__global__ __launch_bounds__(256)
void gemm_out(const uint16_t* __restrict__ A, const uint16_t* __restrict__ Bt,
              const float* __restrict__ bias, float* __restrict__ C) {
  __shared__ uint16_t smem[2 * 2 * 128 * 64];  // 64 KiB
  const int tid = threadIdx.x;
  const int wave = tid >> 6, lane = tid & 63;
  const int l15 = lane & 15, l4 = lane >> 4;
  const int brow = blockIdx.x * 128, bcol = blockIdx.y * 128;
  const int wr = (wave >> 1) * 64, wc = (wave & 1) * 64;

  const f32x4 fzero = {0.f, 0.f, 0.f, 0.f};
  f32x4 acc[4][4];
#pragma unroll
  for (int m = 0; m < 4; ++m)
#pragma unroll
    for (int n = 0; n < 4; ++n) acc[m][n] = fzero;

  gemm_stage(A, Bt, brow, bcol, 0, (char*)smem, 0, wave, lane);
  int cur = 0;
  for (int k0 = 0; k0 < DM; k0 += 64) {
    __syncthreads();
    if (k0 + 64 < DM)
      gemm_stage(A, Bt, brow, bcol, k0 + 64, (char*)smem, cur ^ 1, wave, lane);
    const uint16_t* At = smem + cur * 16384;
    const uint16_t* Bs = At + 8192;
#pragma unroll
    for (int ks = 0; ks < 2; ++ks) {
      bf16x8 a[4], b[4];
#pragma unroll
      for (int m = 0; m < 4; ++m)
        a[m] = *(const bf16x8*)(At + (wr + m * 16 + l15) * 64 + ks * 32 + l4 * 8);
#pragma unroll
      for (int n = 0; n < 4; ++n)
        b[n] = *(const bf16x8*)(Bs + (wc + n * 16 + l15) * 64 + ks * 32 + l4 * 8);
#pragma unroll
      for (int m = 0; m < 4; ++m)
#pragma unroll
        for (int n = 0; n < 4; ++n)
          acc[m][n] = __builtin_amdgcn_mfma_f32_16x16x32_bf16(a[m], b[n], acc[m][n], 0, 0, 0);
    }
    cur ^= 1;
  }

#pragma unroll
  for (int m = 0; m < 4; ++m) {
#pragma unroll
    for (int n = 0; n < 4; ++n) {
      const int gcol = bcol + wc + n * 16 + l15;
      const float bv = bias[gcol];
#pragma unroll
      for (int r = 0; r < 4; ++r) {
        const int grow = brow + wr + m * 16 + l4 * 4 + r;
        C[(size_t)grow * DM + gcol] = acc[m][n][r] + bv;
      }
    }
  }
}

// ---- flash attention: 8 waves = 4 q-subtiles x 2 kv-halves ----
// Block = (b, h, 128 q-rows), 512 threads. Wave (wq = w&3, kh = w>>2):
// q-subtile wq (32 rows), k-half kh (1024 rows = 16 tiles of 64).
// Each half streams its own 32KB double-buffered LDS region (64 KiB total)
// -> 2 blocks/CU, 16 waves/CU (2x the 4-wave version's occupancy).
// End: kh=1 dumps (oacc,m,l) to LDS; kh=0 does exact f32 flash-merge + store.
// Swapped QK^T (mfma(K,Q) -> S^T), per-lane softmax (q = lane&31),
// in-register P via cvt_pk + permlane32_swap, row-sum l via mfma(ones,P).
__device__ __forceinline__ void stage_kv(const uint16_t* __restrict__ Kg,
                                         const uint16_t* __restrict__ Vg,
                                         char* buf, int wq, int lane) {
#pragma unroll
  for (int i = 0; i < 2; ++i) {
    const int base = i * 4096 + wq * 1024;
    const int row = i * 32 + wq * 8 + (lane >> 3);
    const int esw = (((lane & 7) << 4) ^ fsw(row)) >> 1;
    gload_lds16(Kg + (size_t)row * DM + esw, buf + base);
    gload_lds16(Vg + (size_t)row * SEQLEN + esw, buf + 8192 + base);
  }
}

__global__ __launch_bounds__(512)
void attn_fwd_kernel(const uint16_t* __restrict__ Qp, const uint16_t* __restrict__ Kp,
                     const uint16_t* __restrict__ VTp, uint16_t* __restrict__ Op) {
  __shared__ __align__(16) char lds[65536];  // 2 kv-halves x 2 bufs x (K8K|V8K)
  const int swz = (blockIdx.x & 7) * 64 + (blockIdx.x >> 3);  // 512%8==0
  const int bb = swz >> 8, h = (swz >> 4) & 15;
  const int q0 = (swz & 15) * 128;
  const int tid = threadIdx.x;
  const int wave = tid >> 6, lane = tid & 63;
  const int wq = wave & 3, kh = wave >> 2;
  const int l31 = lane & 31, hi = lane >> 5;

  // Q (pre-scaled) in registers: qf[ds] = Q[qrow][ds*16 + hi*8 .. +8].
  const int qrow = q0 + wq * 32 + l31;
  const uint16_t* qb = Qp + ((size_t)(bb * SEQLEN + qrow)) * DM + h * DKH;
  bf16x8 qf[4];
#pragma unroll
  for (int ds = 0; ds < 4; ++ds)
    qf[ds] = *(const bf16x8*)(qb + ds * 16 + hi * 8);

  bf16x8 onesf;
#pragma unroll
  for (int j = 0; j < 8; ++j) onesf[j] = (short)0x3F80;  // bf16 1.0

  f32x16 oacc[2], lacc, zero16;
#pragma unroll
  for (int r = 0; r < 16; ++r) {
    oacc[0][r] = 0.f; oacc[1][r] = 0.f; lacc[r] = 0.f; zero16[r] = 0.f;
  }
  float mrow = -1e30f;

  // This wave's k-half base pointers.
  const uint16_t* Kg = Kp + ((size_t)(bb * SEQLEN + kh * 1024)) * DM + h * DKH;
  const uint16_t* Vg = VTp + ((size_t)((bb * NHEAD + h) * DKH)) * SEQLEN + kh * 1024;
  char* my = lds + kh * 32768;

  stage_kv(Kg, Vg, my, wq, lane);  // tile 0 of this half -> buf 0

  const int NT = 1024 / 64;  // 16 tiles per half
  for (int t = 0; t < NT; ++t) {
    __syncthreads();  // tile t resident (vmcnt drained); buf t+1 free
    if (t + 1 < NT)
      stage_kv(Kg + (size_t)(t + 1) * 64 * DM, Vg + (t + 1) * 64,
               my + ((t + 1) & 1) * 16384, wq, lane);
    const char* kb = my + (t & 1) * 16384;
    const char* vb = kb + 8192;

    // S^T = K Q^T via 32x32x16 (8 MFMA), C-in from never-written zero16.
    f32x16 sacc[2];
    __builtin_amdgcn_s_setprio(1);
#pragma unroll
    for (int n = 0; n < 2; ++n) {
      const int kr = 32 * n + l31;
      const char* krow = kb + kr * 128;
      const int f = fsw(kr);
      const bf16x8 kf0 = *(const bf16x8*)(krow + ((hi * 16) ^ f));
      sacc[n] = __builtin_amdgcn_mfma_f32_32x32x16_bf16(kf0, qf[0], zero16, 0, 0, 0);
#pragma unroll
      for (int ds = 1; ds < 4; ++ds) {
        const bf16x8 kf = *(const bf16x8*)(krow + ((ds * 32 + hi * 16) ^ f));
        sacc[n] = __builtin_amdgcn_mfma_f32_32x32x16_bf16(kf, qf[ds], sacc[n], 0, 0, 0);
      }
    }
    __builtin_amdgcn_s_setprio(0);

    // Max-reduce via v_max3 trees, one cross-half shfl.
    float ma = max3f(sacc[0][0], sacc[0][1], sacc[0][2]);
    ma = max3f(ma, sacc[0][3], sacc[0][4]);
    ma = max3f(ma, sacc[0][5], sacc[0][6]);
    ma = max3f(ma, sacc[0][7], sacc[0][8]);
    ma = max3f(ma, sacc[0][9], sacc[0][10]);
    ma = max3f(ma, sacc[0][11], sacc[0][12]);
    ma = max3f(ma, sacc[0][13], sacc[0][14]);
    float mb = max3f(sacc[1][0], sacc[1][1], sacc[1][2]);
    mb = max3f(mb, sacc[1][3], sacc[1][4]);
    mb = max3f(mb, sacc[1][5], sacc[1][6]);
    mb = max3f(mb, sacc[1][7], sacc[1][8]);
    mb = max3f(mb, sacc[1][9], sacc[1][10]);
    mb = max3f(mb, sacc[1][11], sacc[1][12]);
    mb = max3f(mb, sacc[1][13], sacc[1][14]);
    float mx = max3f(fmaxf(ma, sacc[0][15]), mb, sacc[1][15]);
    mx = fmaxf(mx, __shfl_xor(mx, 32, 64));

    float mnew = mrow;
    if (__any(mx > mrow + 8.f)) {  // defer-max THR=8 (P bounded by 2^8)
      mnew = fmaxf(mrow, mx);
      const float scl = exp2_fast(mrow - mnew);
#pragma unroll
      for (int m = 0; m < 2; ++m)
#pragma unroll
        for (int r = 0; r < 16; ++r) oacc[m][r] *= scl;
      lacc[0] *= scl;
    }
    mrow = mnew;

#pragma unroll
    for (int n = 0; n < 2; ++n) {
      float pv[16];
#pragma unroll
      for (int r = 0; r < 16; ++r) pv[r] = exp2_fast(sacc[n][r] - mnew);
      // In-register P->bf16 fragments (T12): cvt_pk pairs + permlane32_swap
      // assemble contiguous k 0..15 (f0) / 16..31 (f1) B-fragments.
      const uint32_t c0 = cvtpk(pv[0], pv[1]),   c1 = cvtpk(pv[2], pv[3]);
      const uint32_t c2 = cvtpk(pv[4], pv[5]),   c3 = cvtpk(pv[6], pv[7]);
      const uint32_t c4 = cvtpk(pv[8], pv[9]),   c5 = cvtpk(pv[10], pv[11]);
      const uint32_t c6 = cvtpk(pv[12], pv[13]), c7 = cvtpk(pv[14], pv[15]);
      const u32x2 r02 = __builtin_amdgcn_permlane32_swap(c0, c2, false, false);
      const u32x2 r13 = __builtin_amdgcn_permlane32_swap(c1, c3, false, false);
      const u32x2 r46 = __builtin_amdgcn_permlane32_swap(c4, c6, false, false);
      const u32x2 r57 = __builtin_amdgcn_permlane32_swap(c5, c7, false, false);
      union { uint32_t w[4]; bf16x8 v; } f0, f1;
      f0.w[0] = r02.x; f0.w[1] = r13.x; f0.w[2] = r02.y; f0.w[3] = r13.y;
      f1.w[0] = r46.x; f1.w[1] = r57.x; f1.w[2] = r46.y; f1.w[3] = r57.y;

      // O^T += V^T P^T; l += 1^T P^T (row-sum on the MFMA pipe).
      __builtin_amdgcn_s_setprio(1);
#pragma unroll
      for (int m = 0; m < 2; ++m) {
        const int vr = 32 * m + l31;
        const char* vrow = vb + vr * 128;
        const int f = fsw(vr);
        const bf16x8 v0 = *(const bf16x8*)(vrow + ((n * 64 + hi * 16) ^ f));
        const bf16x8 v1 = *(const bf16x8*)(vrow + ((n * 64 + 32 + hi * 16) ^ f));
        oacc[m] = __builtin_amdgcn_mfma_f32_32x32x16_bf16(v0, f0.v, oacc[m], 0, 0, 0);
        oacc[m] = __builtin_amdgcn_mfma_f32_32x32x16_bf16(v1, f1.v, oacc[m], 0, 0, 0);
      }
      lacc = __builtin_amdgcn_mfma_f32_32x32x16_bf16(onesf, f0.v, lacc, 0, 0, 0);
      lacc = __builtin_amdgcn_mfma_f32_32x32x16_bf16(onesf, f1.v, lacc, 0, 0, 0);
      __builtin_amdgcn_s_setprio(0);
    }
  }

  // ---- merge the two k-halves (exact, f32) ----
  __syncthreads();  // all staging reads done; LDS reusable as merge scratch
  char* mbuf = lds + wq * 16384 + lane * 144;  // 144B/lane, 16B-aligned
  if (kh == 1) {
    *(f32x16*)(mbuf) = oacc[0];
    *(f32x16*)(mbuf + 64) = oacc[1];
    *(float*)(mbuf + 128) = mrow;
    *(float*)(mbuf + 132) = lacc[0];
  }
  __syncthreads();
  if (kh == 1) return;

  const f32x16 o2a = *(const f32x16*)(mbuf);
  const f32x16 o2b = *(const f32x16*)(mbuf + 64);
  const float m2 = *(const float*)(mbuf + 128);
  const float l2 = *(const float*)(mbuf + 132);
  const float mstar = fmaxf(mrow, m2);
  const float a1 = exp2_fast(mrow - mstar);
  const float a2 = exp2_fast(m2 - mstar);
  const float il = 1.0f / (a1 * lacc[0] + a2 * l2);
  const float w1 = a1 * il, w2 = a2 * il;

  // Normalize + store. oacc[m][r] = O^T[d][q=l31], d = 32m+(r&3)+8(r>>2)+4hi.
  uint16_t* ob = Op + ((size_t)(bb * SEQLEN + qrow)) * DM + h * DKH;
#pragma unroll
  for (int m = 0; m < 2; ++m) {
    const f32x16 o2 = (m == 0) ? o2a : o2b;
#pragma unroll
    for (int rq = 0; rq < 4; ++rq) {
      const uint32_t w0 = cvtpk(oacc[m][4 * rq + 0] * w1 + o2[4 * rq + 0] * w2,
                                oacc[m][4 * rq + 1] * w1 + o2[4 * rq + 1] * w2);
      const uint32_t wA = cvtpk(oacc[m][4 * rq + 2] * w1 + o2[4 * rq + 2] * w2,
                                oacc[m][4 * rq + 3] * w1 + o2[4 * rq + 3] * w2);
      *(uint64_t*)(ob + 32 * m + 8 * rq + 4 * hi) =
          (uint64_t)w0 | ((uint64_t)wA << 32);
    }
  }
}

extern "C" void kernel_launch(void* const* d_in, const int* in_sizes, int n_in,
                              void* d_out, int out_size, void* d_ws, size_t ws_size,
                              hipStream_t stream) {
  (void)in_sizes; (void)n_in; (void)out_size; (void)ws_size;
  const float* query = (const float*)d_in[0];
  const float* key_i = (const float*)d_in[1];
  const float* value = (const float*)d_in[2];
  const float* Wq = (const float*)d_in[3];
  const float* bq = (const float*)d_in[4];
  const float* Wk = (const float*)d_in[5];
  const float* bk = (const float*)d_in[6];
  const float* Wv = (const float*)d_in[7];
  const float* bv = (const float*)d_in[8];
  const float* Wo = (const float*)d_in[9];
  const float* bo = (const float*)d_in[10];
  float* out = (float*)d_out;

  char* ws = (char*)d_ws;
  const size_t MB = 1ull << 20;
  uint16_t* xq  = (uint16_t*)(ws + 0 * MB);    // 8 MB each (4096x1024 bf16)
  uint16_t* xk  = (uint16_t*)(ws + 8 * MB);
  uint16_t* xv  = (uint16_t*)(ws + 16 * MB);
  uint16_t* wqkv = (uint16_t*)(ws + 24 * MB);  // 3 x 2 MB contiguous (q,k,v)
  uint16_t* wob = (uint16_t*)(ws + 30 * MB);
  uint16_t* Qp  = (uint16_t*)(ws + 32 * MB);   // [s][dm], Q pre-scaled
  uint16_t* Kp  = (uint16_t*)(ws + 40 * MB);   // [s][dm]
  uint16_t* VTp = (uint16_t*)(ws + 48 * MB);   // [b,h,d,s]
  uint16_t* AO  = (uint16_t*)(ws + 56 * MB);   // [s][dm], ends at 64 MB

  const int n4x = (MTOT * DM) / 4;
  const int n4w = (DM * DM) / 4;
  CvtArgs ca;
  ca.src[0] = query; ca.dst[0] = xq;
  ca.src[1] = key_i; ca.dst[1] = xk;
  ca.src[2] = value; ca.dst[2] = xv;
  ca.src[3] = Wq;    ca.dst[3] = wqkv;
  ca.src[4] = Wk;    ca.dst[4] = wqkv + DM * DM;
  ca.src[5] = Wv;    ca.dst[5] = wqkv + 2 * DM * DM;
  ca.src[6] = Wo;    ca.dst[6] = wob;
  int acc = 0;
  for (int j = 0; j < 7; ++j) { acc += (j < 3) ? n4x : n4w; ca.end4[j] = acc; }
  const int blk = 256;
  cvt_all_kernel<<<(acc + blk - 1) / blk, blk, 0, stream>>>(ca);

  dim3 gq(MTOT / 128, 24);  // 32 x 24 = 768 blocks, 3 projections fused
  gemm_qkv<<<gq, 256, 0, stream>>>(xq, xk, xv, wqkv, bq, bk, bv, Qp, Kp, VTp);

  attn_fwd_kernel<<<512, 512, 0, stream>>>(Qp, Kp, VTp, AO);

  dim3 gg(MTOT / 128, DM / 128);  // 32 x 8
  gemm_out<<<gg, 256, 0, stream>>>(AO, wob, bo, out);
}

// Round 11
// 125.862 us; speedup vs baseline: 1.2285x; 1.0070x over previous
//
#include <hip/hip_runtime.h>
#include <cstdint>
#include <cstddef>

#define DM 1024
#define NHEAD 16
#define DKH 64
#define SEQLEN 2048
#define NBATCH 2
#define MTOT (NBATCH * SEQLEN)  // 4096

typedef __attribute__((ext_vector_type(8))) short bf16x8;
typedef __attribute__((ext_vector_type(4))) float f32x4;
typedef __attribute__((ext_vector_type(16))) float f32x16;
typedef __attribute__((ext_vector_type(2))) unsigned int u32x2;

// (1/sqrt(Dk)) * log2(e): folded into Q projection; attn softmax uses exp2.
#define QSCALE 0.18033688011112042f

__device__ __forceinline__ uint16_t f2bf(float f) {
  uint32_t x = __float_as_uint(f);
  uint32_t r = x + 0x7FFFu + ((x >> 16) & 1u);  // RNE; inputs finite
  return (uint16_t)(r >> 16);
}

__device__ __forceinline__ uint32_t cvtpk(float a, float b) {
  uint32_t r;
  asm("v_cvt_pk_bf16_f32 %0, %1, %2" : "=v"(r) : "v"(a), "v"(b));
  return r;
}

__device__ __forceinline__ float exp2_fast(float x) {
  float r;
  asm("v_exp_f32 %0, %1" : "=v"(r) : "v"(x));
  return r;
}

__device__ __forceinline__ float max3f(float a, float b, float c) {
  float r;
  asm("v_max3_f32 %0, %1, %2, %3" : "=v"(r) : "v"(a), "v"(b), "v"(c));
  return r;
}

__device__ __forceinline__ void gload_lds16(const void* g, void* l) {
  __builtin_amdgcn_global_load_lds(
      (const __attribute__((address_space(1))) void*)g,
      (__attribute__((address_space(3))) void*)l, 16, 0, 0);
}

// Swizzle: 16B-slot XOR (bits 4-6) so 32-row column reads spread over 8 slots.
__device__ __forceinline__ int fsw(int r) { return ((r + (r >> 3)) & 7) << 4; }

// ---- fused fp32 -> bf16 convert over 7 regions in one launch ----
struct CvtArgs {
  const float* src[7];
  uint16_t* dst[7];
  int end4[7];  // cumulative float4 counts
};

__global__ void cvt_all_kernel(CvtArgs a) {
  int i = blockIdx.x * blockDim.x + threadIdx.x;
  int r = 0;
#pragma unroll
  for (int j = 0; j < 7; ++j)
    if (i >= a.end4[j]) r = j + 1;
  if (r >= 7) return;
  int local = i - (r == 0 ? 0 : a.end4[r - 1]);
  float4 v = reinterpret_cast<const float4*>(a.src[r])[local];
  uint64_t p = (uint64_t)f2bf(v.x) | ((uint64_t)f2bf(v.y) << 16) |
               ((uint64_t)f2bf(v.z) << 32) | ((uint64_t)f2bf(v.w) << 48);
  reinterpret_cast<uint64_t*>(a.dst[r])[local] = p;
}

// ---- fused QKV projection GEMM: BK=32, LDS 32 KiB -> 3 blocks/CU co-resident ----
// grid (M/128, 24): blockIdx.y>>3 selects projection (0=Q,1=K,2=V).
// C = A @ W^T + b; Q scaled by QSCALE; V written transposed to [b,h,d,s].
// Stage tile s (A 128x32 + Bt 128x32 = 16 KiB) into buf s&1.
__device__ __forceinline__ void qkv_stage(const uint16_t* __restrict__ A,
                                          const uint16_t* __restrict__ Bt,
                                          int brow, int bcol, int k0,
                                          uint16_t* smem, int buf, int wave, int lane) {
#pragma unroll
  for (int t = 0; t < 4; ++t) {
    const int c = wave * 4 + t;          // 1 KiB chunk, 0..15
    const int o = c * 1024 + lane * 16;  // byte offset within the 16 KiB buf
    const uint16_t* g;
    if (c < 8) {  // A region: 128 rows x 64 B
      const int row = o >> 6, kk = (o & 63) >> 1;
      g = A + (size_t)(brow + row) * DM + (k0 + kk);
    } else {      // B region
      const int o2 = o - 8192;
      const int row = o2 >> 6, kk = (o2 & 63) >> 1;
      g = Bt + (size_t)(bcol + row) * DM + (k0 + kk);
    }
    gload_lds16(g, (char*)smem + buf * 16384 + c * 1024);
  }
}

__global__ __launch_bounds__(256)
void gemm_qkv(const uint16_t* __restrict__ xq, const uint16_t* __restrict__ xk,
              const uint16_t* __restrict__ xv, const uint16_t* __restrict__ wqkv,
              const float* __restrict__ bqp, const float* __restrict__ bkp,
              const float* __restrict__ bvp, uint16_t* __restrict__ Qp,
              uint16_t* __restrict__ Kp, uint16_t* __restrict__ VTp) {
  __shared__ uint16_t smem[2 * 8192];  // 32 KiB: 2 bufs x (A 8K | B 8K)
  const int tid = threadIdx.x;
  const int wave = tid >> 6, lane = tid & 63;
  const int l15 = lane & 15, l4 = lane >> 4;
  const int proj = blockIdx.y >> 3;
  const int brow = blockIdx.x * 128, bcol = (blockIdx.y & 7) * 128;
  const int wr = (wave >> 1) * 64, wc = (wave & 1) * 64;
  const uint16_t* A = proj == 0 ? xq : proj == 1 ? xk : xv;
  const uint16_t* Bt = wqkv + (size_t)proj * DM * DM;
  const float* bias = proj == 0 ? bqp : proj == 1 ? bkp : bvp;

  const f32x4 fzero = {0.f, 0.f, 0.f, 0.f};
  f32x4 acc[4][4];
#pragma unroll
  for (int m = 0; m < 4; ++m)
#pragma unroll
    for (int n = 0; n < 4; ++n) acc[m][n] = fzero;

  qkv_stage(A, Bt, brow, bcol, 0, smem, 0, wave, lane);
  int cur = 0;
  for (int k0 = 0; k0 < DM; k0 += 32) {
    __syncthreads();  // loads for buf[cur] drained; buf[cur^1] free of readers
    if (k0 + 32 < DM)
      qkv_stage(A, Bt, brow, bcol, k0 + 32, smem, cur ^ 1, wave, lane);
    const uint16_t* At = smem + cur * 8192;
    const uint16_t* Bs = At + 4096;
    bf16x8 a[4], b[4];
#pragma unroll
    for (int m = 0; m < 4; ++m)
      a[m] = *(const bf16x8*)(At + (wr + m * 16 + l15) * 32 + l4 * 8);
#pragma unroll
    for (int n = 0; n < 4; ++n)
      b[n] = *(const bf16x8*)(Bs + (wc + n * 16 + l15) * 32 + l4 * 8);
#pragma unroll
    for (int m = 0; m < 4; ++m)
#pragma unroll
      for (int n = 0; n < 4; ++n)
        acc[m][n] = __builtin_amdgcn_mfma_f32_16x16x32_bf16(a[m], b[n], acc[m][n], 0, 0, 0);
    cur ^= 1;
  }

  const float scale = proj == 0 ? QSCALE : 1.0f;
  uint16_t* dstQK = proj == 0 ? Qp : Kp;
#pragma unroll
  for (int m = 0; m < 4; ++m) {
#pragma unroll
    for (int n = 0; n < 4; ++n) {
      const int gcol = bcol + wc + n * 16 + l15;
      const float bv = bias[gcol];
      if (proj == 2) {
        // V^T: element (s=grow, col=gcol) -> VT[(b*NHEAD+h)*DKH + d][s].
        const int grow0 = brow + wr + m * 16 + l4 * 4;
        const int b_ = grow0 >> 11, s_ = grow0 & 2047;
        const int h_ = gcol >> 6, d_ = gcol & 63;
        uint16_t* dst = VTp + ((size_t)((b_ * NHEAD + h_) * DKH + d_)) * SEQLEN + s_;
        uint64_t pk = (uint64_t)f2bf(acc[m][n][0] + bv) |
                      ((uint64_t)f2bf(acc[m][n][1] + bv) << 16) |
                      ((uint64_t)f2bf(acc[m][n][2] + bv) << 32) |
                      ((uint64_t)f2bf(acc[m][n][3] + bv) << 48);
        *(uint64_t*)dst = pk;
      } else {
#pragma unroll
        for (int r = 0; r < 4; ++r) {
          const int grow = brow + wr + m * 16 + l4 * 4 + r;
          dstQK[(size_t)grow * DM + gcol] = f2bf((acc[m][n][r] + bv) * scale);
        }
      }
    }
  }
}

// Stage one 128x64 A-tile + 128x64 B-tile (32 KiB) into LDS buffer `buf`.
__device__ __forceinline__ void gemm_stage(const uint16_t* __restrict__ A,
                                           const uint16_t* __restrict__ Bt,
                                           int brow, int bcol, int k0,
                                           char* smem, int buf, int wave, int lane) {
#pragma unroll
  for (int t = 0; t < 8; ++t) {
    const int o = t * 4096 + wave * 1024 + lane * 16;
    const uint16_t* g;
    if (t < 4) {
      const int row = o >> 7, kk = (o & 127) >> 1;
      g = A + (size_t)(brow + row) * DM + (k0 + kk);
    } else {
      const int o2 = o - 16384;
      const int row = o2 >> 7, kk = (o2 & 127) >> 1;
      g = Bt + (size_t)(bcol + row) * DM + (k0 + kk);
    }
    gload_lds16(g, smem + buf * 32768 + t * 4096 + wave * 1024);
  }
}

// ---- output projection GEMM (f32 out, 2-phase double-buffered, BK=64) ----
__global__ __launch_bounds__(256)
void gemm_out(const uint16_t* __restrict__ A, const uint16_t* __restrict__ Bt,
              const float* __restrict__ bias, float* __restrict__ C) {
  __shared__ uint16_t smem[2 * 2 * 128 * 64];  // 64 KiB
  const int tid = threadIdx.x;
  const int wave = tid >> 6, lane = tid & 63;
  const int l15 = lane & 15, l4 = lane >> 4;
  const int brow = blockIdx.x * 128, bcol = blockIdx.y * 128;
  const int wr = (wave >> 1) * 64, wc = (wave & 1) * 64;

  const f32x4 fzero = {0.f, 0.f, 0.f, 0.f};
  f32x4 acc[4][4];
#pragma unroll
  for (int m = 0; m < 4; ++m)
#pragma unroll
    for (int n = 0; n < 4; ++n) acc[m][n] = fzero;

  gemm_stage(A, Bt, brow, bcol, 0, (char*)smem, 0, wave, lane);
  int cur = 0;
  for (int k0 = 0; k0 < DM; k0 += 64) {
    __syncthreads();
    if (k0 + 64 < DM)
      gemm_stage(A, Bt, brow, bcol, k0 + 64, (char*)smem, cur ^ 1, wave, lane);
    const uint16_t* At = smem + cur * 16384;
    const uint16_t* Bs = At + 8192;
#pragma unroll
    for (int ks = 0; ks < 2; ++ks) {
      bf16x8 a[4], b[4];
#pragma unroll
      for (int m = 0; m < 4; ++m)
        a[m] = *(const bf16x8*)(At + (wr + m * 16 + l15) * 64 + ks * 32 + l4 * 8);
#pragma unroll
      for (int n = 0; n < 4; ++n)
        b[n] = *(const bf16x8*)(Bs + (wc + n * 16 + l15) * 64 + ks * 32 + l4 * 8);
#pragma unroll
      for (int m = 0; m < 4; ++m)
#pragma unroll
        for (int n = 0; n < 4; ++n)
          acc[m][n] = __builtin_amdgcn_mfma_f32_16x16x32_bf16(a[m], b[n], acc[m][n], 0, 0, 0);
    }
    cur ^= 1;
  }

#pragma unroll
  for (int m = 0; m < 4; ++m) {
#pragma unroll
    for (int n = 0; n < 4; ++n) {
      const int gcol = bcol + wc + n * 16 + l15;
      const float bv = bias[gcol];
#pragma unroll
      for (int r = 0; r < 4; ++r) {
        const int grow = brow + wr + m * 16 + l4 * 4 + r;
        C[(size_t)grow * DM + gcol] = acc[m][n][r] + bv;
      }
    }
  }
}

// ---- flash attention: 8 waves = 4 q-subtiles x 2 kv-halves ----
// Block = (b, h, 128 q-rows), 512 threads. Wave (wq = w&3, kh = w>>2):
// q-subtile wq (32 rows), k-half kh (1024 rows = 16 tiles of 64).
// Each half streams its own 32KB double-buffered LDS region (64 KiB total).
// End: kh=1 dumps (oacc,m,l) to LDS; kh=0 does exact f32 flash-merge + store.
// Swapped QK^T (mfma(K,Q) -> S^T), per-lane softmax (q = lane&31),
// in-register P via cvt_pk + permlane32_swap, row-sum l via mfma(ones,P).
__device__ __forceinline__ void stage_kv(const uint16_t* __restrict__ Kg,
                                         const uint16_t* __restrict__ Vg,
                                         char* buf, int wq, int lane) {
#pragma unroll
  for (int i = 0; i < 2; ++i) {
    const int base = i * 4096 + wq * 1024;
    const int row = i * 32 + wq * 8 + (lane >> 3);
    const int esw = (((lane & 7) << 4) ^ fsw(row)) >> 1;
    gload_lds16(Kg + (size_t)row * DM + esw, buf + base);
    gload_lds16(Vg + (size_t)row * SEQLEN + esw, buf + 8192 + base);
  }
}

__global__ __launch_bounds__(512)
void attn_fwd_kernel(const uint16_t* __restrict__ Qp, const uint16_t* __restrict__ Kp,
                     const uint16_t* __restrict__ VTp, uint16_t* __restrict__ Op) {
  __shared__ __align__(16) char lds[65536];  // 2 kv-halves x 2 bufs x (K8K|V8K)
  const int swz = (blockIdx.x & 7) * 64 + (blockIdx.x >> 3);  // 512%8==0
  const int bb = swz >> 8, h = (swz >> 4) & 15;
  const int q0 = (swz & 15) * 128;
  const int tid = threadIdx.x;
  const int wave = tid >> 6, lane = tid & 63;
  const int wq = wave & 3, kh = wave >> 2;
  const int l31 = lane & 31, hi = lane >> 5;

  // Q (pre-scaled) in registers: qf[ds] = Q[qrow][ds*16 + hi*8 .. +8].
  const int qrow = q0 + wq * 32 + l31;
  const uint16_t* qb = Qp + ((size_t)(bb * SEQLEN + qrow)) * DM + h * DKH;
  bf16x8 qf[4];
#pragma unroll
  for (int ds = 0; ds < 4; ++ds)
    qf[ds] = *(const bf16x8*)(qb + ds * 16 + hi * 8);

  bf16x8 onesf;
#pragma unroll
  for (int j = 0; j < 8; ++j) onesf[j] = (short)0x3F80;  // bf16 1.0

  f32x16 oacc[2], lacc, zero16;
#pragma unroll
  for (int r = 0; r < 16; ++r) {
    oacc[0][r] = 0.f; oacc[1][r] = 0.f; lacc[r] = 0.f; zero16[r] = 0.f;
  }
  float mrow = -1e30f;

  // This wave's k-half base pointers.
  const uint16_t* Kg = Kp + ((size_t)(bb * SEQLEN + kh * 1024)) * DM + h * DKH;
  const uint16_t* Vg = VTp + ((size_t)((bb * NHEAD + h) * DKH)) * SEQLEN + kh * 1024;
  char* my = lds + kh * 32768;

  stage_kv(Kg, Vg, my, wq, lane);  // tile 0 of this half -> buf 0

  const int NT = 1024 / 64;  // 16 tiles per half
  for (int t = 0; t < NT; ++t) {
    __syncthreads();  // tile t resident (vmcnt drained); buf t+1 free
    if (t + 1 < NT)
      stage_kv(Kg + (size_t)(t + 1) * 64 * DM, Vg + (t + 1) * 64,
               my + ((t + 1) & 1) * 16384, wq, lane);
    const char* kb = my + (t & 1) * 16384;
    const char* vb = kb + 8192;

    // S^T = K Q^T via 32x32x16 (8 MFMA), C-in from never-written zero16.
    f32x16 sacc[2];
    __builtin_amdgcn_s_setprio(1);
#pragma unroll
    for (int n = 0; n < 2; ++n) {
      const int kr = 32 * n + l31;
      const char* krow = kb + kr * 128;
      const int f = fsw(kr);
      const bf16x8 kf0 = *(const bf16x8*)(krow + ((hi * 16) ^ f));
      sacc[n] = __builtin_amdgcn_mfma_f32_32x32x16_bf16(kf0, qf[0], zero16, 0, 0, 0);
#pragma unroll
      for (int ds = 1; ds < 4; ++ds) {
        const bf16x8 kf = *(const bf16x8*)(krow + ((ds * 32 + hi * 16) ^ f));
        sacc[n] = __builtin_amdgcn_mfma_f32_32x32x16_bf16(kf, qf[ds], sacc[n], 0, 0, 0);
      }
    }
    __builtin_amdgcn_s_setprio(0);

    // Max-reduce via v_max3 trees, one cross-half shfl.
    float ma = max3f(sacc[0][0], sacc[0][1], sacc[0][2]);
    ma = max3f(ma, sacc[0][3], sacc[0][4]);
    ma = max3f(ma, sacc[0][5], sacc[0][6]);
    ma = max3f(ma, sacc[0][7], sacc[0][8]);
    ma = max3f(ma, sacc[0][9], sacc[0][10]);
    ma = max3f(ma, sacc[0][11], sacc[0][12]);
    ma = max3f(ma, sacc[0][13], sacc[0][14]);
    float mb = max3f(sacc[1][0], sacc[1][1], sacc[1][2]);
    mb = max3f(mb, sacc[1][3], sacc[1][4]);
    mb = max3f(mb, sacc[1][5], sacc[1][6]);
    mb = max3f(mb, sacc[1][7], sacc[1][8]);
    mb = max3f(mb, sacc[1][9], sacc[1][10]);
    mb = max3f(mb, sacc[1][11], sacc[1][12]);
    mb = max3f(mb, sacc[1][13], sacc[1][14]);
    float mx = max3f(fmaxf(ma, sacc[0][15]), mb, sacc[1][15]);
    mx = fmaxf(mx, __shfl_xor(mx, 32, 64));

    float mnew = mrow;
    if (__any(mx > mrow + 8.f)) {  // defer-max THR=8 (P bounded by 2^8)
      mnew = fmaxf(mrow, mx);
      const float scl = exp2_fast(mrow - mnew);
#pragma unroll
      for (int m = 0; m < 2; ++m)
#pragma unroll
        for (int r = 0; r < 16; ++r) oacc[m][r] *= scl;
      lacc[0] *= scl;
    }
    mrow = mnew;

#pragma unroll
    for (int n = 0; n < 2; ++n) {
      float pv[16];
#pragma unroll
      for (int r = 0; r < 16; ++r) pv[r] = exp2_fast(sacc[n][r] - mnew);
      // In-register P->bf16 fragments (T12): cvt_pk pairs + permlane32_swap
      // assemble contiguous k 0..15 (f0) / 16..31 (f1) B-fragments.
      const uint32_t c0 = cvtpk(pv[0], pv[1]),   c1 = cvtpk(pv[2], pv[3]);
      const uint32_t c2 = cvtpk(pv[4], pv[5]),   c3 = cvtpk(pv[6], pv[7]);
      const uint32_t c4 = cvtpk(pv[8], pv[9]),   c5 = cvtpk(pv[10], pv[11]);
      const uint32_t c6 = cvtpk(pv[12], pv[13]), c7 = cvtpk(pv[14], pv[15]);
      const u32x2 r02 = __builtin_amdgcn_permlane32_swap(c0, c2, false, false);
      const u32x2 r13 = __builtin_amdgcn_permlane32_swap(c1, c3, false, false);
      const u32x2 r46 = __builtin_amdgcn_permlane32_swap(c4, c6, false, false);
      const u32x2 r57 = __builtin_amdgcn_permlane32_swap(c5, c7, false, false);
      union { uint32_t w[4]; bf16x8 v; } f0, f1;
      f0.w[0] = r02.x; f0.w[1] = r13.x; f0.w[2] = r02.y; f0.w[3] = r13.y;
      f1.w[0] = r46.x; f1.w[1] = r57.x; f1.w[2] = r46.y; f1.w[3] = r57.y;

      // O^T += V^T P^T; l += 1^T P^T (row-sum on the MFMA pipe).
      __builtin_amdgcn_s_setprio(1);
#pragma unroll
      for (int m = 0; m < 2; ++m) {
        const int vr = 32 * m + l31;
        const char* vrow = vb + vr * 128;
        const int f = fsw(vr);
        const bf16x8 v0 = *(const bf16x8*)(vrow + ((n * 64 + hi * 16) ^ f));
        const bf16x8 v1 = *(const bf16x8*)(vrow + ((n * 64 + 32 + hi * 16) ^ f));
        oacc[m] = __builtin_amdgcn_mfma_f32_32x32x16_bf16(v0, f0.v, oacc[m], 0, 0, 0);
        oacc[m] = __builtin_amdgcn_mfma_f32_32x32x16_bf16(v1, f1.v, oacc[m], 0, 0, 0);
      }
      lacc = __builtin_amdgcn_mfma_f32_32x32x16_bf16(onesf, f0.v, lacc, 0, 0, 0);
      lacc = __builtin_amdgcn_mfma_f32_32x32x16_bf16(onesf, f1.v, lacc, 0, 0, 0);
      __builtin_amdgcn_s_setprio(0);
    }
  }

  // ---- merge the two k-halves (exact, f32) ----
  __syncthreads();  // all staging reads done; LDS reusable as merge scratch
  char* mbuf = lds + wq * 16384 + lane * 144;  // 144B/lane, 16B-aligned
  if (kh == 1) {
    *(f32x16*)(mbuf) = oacc[0];
    *(f32x16*)(mbuf + 64) = oacc[1];
    *(float*)(mbuf + 128) = mrow;
    *(float*)(mbuf + 132) = lacc[0];
  }
  __syncthreads();
  if (kh == 1) return;

  const f32x16 o2a = *(const f32x16*)(mbuf);
  const f32x16 o2b = *(const f32x16*)(mbuf + 64);
  const float m2 = *(const float*)(mbuf + 128);
  const float l2 = *(const float*)(mbuf + 132);
  const float mstar = fmaxf(mrow, m2);
  const float a1 = exp2_fast(mrow - mstar);
  const float a2 = exp2_fast(m2 - mstar);
  const float il = 1.0f / (a1 * lacc[0] + a2 * l2);
  const float w1 = a1 * il, w2 = a2 * il;

  // Normalize + store. oacc[m][r] = O^T[d][q=l31], d = 32m+(r&3)+8(r>>2)+4hi.
  uint16_t* ob = Op + ((size_t)(bb * SEQLEN + qrow)) * DM + h * DKH;
#pragma unroll
  for (int m = 0; m < 2; ++m) {
    const f32x16 o2 = (m == 0) ? o2a : o2b;
#pragma unroll
    for (int rq = 0; rq < 4; ++rq) {
      const uint32_t w0 = cvtpk(oacc[m][4 * rq + 0] * w1 + o2[4 * rq + 0] * w2,
                                oacc[m][4 * rq + 1] * w1 + o2[4 * rq + 1] * w2);
      const uint32_t wA = cvtpk(oacc[m][4 * rq + 2] * w1 + o2[4 * rq + 2] * w2,
                                oacc[m][4 * rq + 3] * w1 + o2[4 * rq + 3] * w2);
      *(uint64_t*)(ob + 32 * m + 8 * rq + 4 * hi) =
          (uint64_t)w0 | ((uint64_t)wA << 32);
    }
  }
}

extern "C" void kernel_launch(void* const* d_in, const int* in_sizes, int n_in,
                              void* d_out, int out_size, void* d_ws, size_t ws_size,
                              hipStream_t stream) {
  (void)in_sizes; (void)n_in; (void)out_size; (void)ws_size;
  const float* query = (const float*)d_in[0];
  const float* key_i = (const float*)d_in[1];
  const float* value = (const float*)d_in[2];
  const float* Wq = (const float*)d_in[3];
  const float* bq = (const float*)d_in[4];
  const float* Wk = (const float*)d_in[5];
  const float* bk = (const float*)d_in[6];
  const float* Wv = (const float*)d_in[7];
  const float* bv = (const float*)d_in[8];
  const float* Wo = (const float*)d_in[9];
  const float* bo = (const float*)d_in[10];
  float* out = (float*)d_out;

  char* ws = (char*)d_ws;
  const size_t MB = 1ull << 20;
  uint16_t* xq  = (uint16_t*)(ws + 0 * MB);    // 8 MB each (4096x1024 bf16)
  uint16_t* xk  = (uint16_t*)(ws + 8 * MB);
  uint16_t* xv  = (uint16_t*)(ws + 16 * MB);
  uint16_t* wqkv = (uint16_t*)(ws + 24 * MB);  // 3 x 2 MB contiguous (q,k,v)
  uint16_t* wob = (uint16_t*)(ws + 30 * MB);
  uint16_t* Qp  = (uint16_t*)(ws + 32 * MB);   // [s][dm], Q pre-scaled
  uint16_t* Kp  = (uint16_t*)(ws + 40 * MB);   // [s][dm]
  uint16_t* VTp = (uint16_t*)(ws + 48 * MB);   // [b,h,d,s]
  uint16_t* AO  = (uint16_t*)(ws + 56 * MB);   // [s][dm], ends at 64 MB

  const int n4x = (MTOT * DM) / 4;
  const int n4w = (DM * DM) / 4;
  CvtArgs ca;
  ca.src[0] = query; ca.dst[0] = xq;
  ca.src[1] = key_i; ca.dst[1] = xk;
  ca.src[2] = value; ca.dst[2] = xv;
  ca.src[3] = Wq;    ca.dst[3] = wqkv;
  ca.src[4] = Wk;    ca.dst[4] = wqkv + DM * DM;
  ca.src[5] = Wv;    ca.dst[5] = wqkv + 2 * DM * DM;
  ca.src[6] = Wo;    ca.dst[6] = wob;
  int acc = 0;
  for (int j = 0; j < 7; ++j) { acc += (j < 3) ? n4x : n4w; ca.end4[j] = acc; }
  const int blk = 256;
  cvt_all_kernel<<<(acc + blk - 1) / blk, blk, 0, stream>>>(ca);

  dim3 gq(MTOT / 128, 24);  // 32 x 24 = 768 blocks, 3 projections fused
  gemm_qkv<<<gq, 256, 0, stream>>>(xq, xk, xv, wqkv, bq, bk, bv, Qp, Kp, VTp);

  attn_fwd_kernel<<<512, 512, 0, stream>>>(Qp, Kp, VTp, AO);

  dim3 gg(MTOT / 128, DM / 128);  // 32 x 8
  gemm_out<<<gg, 256, 0, stream>>>(AO, wob, bo, out);
}